// Round 13
// baseline (467.944 us; speedup 1.0000x reference)
//
#include <hip/hip_runtime.h>

#define NN 100000
#define NE 300000
#define DD 128
#define NBLKG 782            // ceil(NN/128) gemm blocks
#define NBLKSEG 49           // ceil(NN/2048) scan blocks per segment

typedef short bf16x8 __attribute__((ext_vector_type(8)));
typedef float f32x4 __attribute__((ext_vector_type(4)));
typedef unsigned u32x4 __attribute__((ext_vector_type(4)));

__device__ __forceinline__ unsigned short f2b(float f) {
    union { float f; unsigned u; } c; c.f = f;
    unsigned u = c.u;
    return (unsigned short)((u + 0x7fffu + ((u >> 16) & 1u)) >> 16);
}
__device__ __forceinline__ float b2lo(unsigned u) {
    union { float f; unsigned u; } c; c.u = u << 16; return c.f;
}
__device__ __forceinline__ float b2hi(unsigned u) {
    union { float f; unsigned u; } c; c.u = u & 0xffff0000u; return c.f;
}
__device__ __forceinline__ unsigned pack2(float lo, float hi) {
    return (unsigned)f2b(lo) | ((unsigned)f2b(hi) << 16);
}

// ---------- feat -> bf16 ----------
__global__ __launch_bounds__(256) void feat_to_bf16(
    const float* __restrict__ feat, unsigned short* __restrict__ fb) {
    int gid = blockIdx.x * 256 + threadIdx.x;
    if (gid >= NN * 16) return;
    const f32x4* f4 = (const f32x4*)feat;
    f32x4 a = __builtin_nontemporal_load(&f4[gid * 2]);      // read-once stream
    f32x4 b = __builtin_nontemporal_load(&f4[gid * 2 + 1]);
    uint4 o;
    o.x = pack2(a.x, a.y); o.y = pack2(a.z, a.w);
    o.z = pack2(b.x, b.y); o.w = pack2(b.z, b.w);
    ((uint4*)fb)[gid] = o;   // featB: keep cacheable (hot random-read operand)
}

// ---------- weight prep ----------
__global__ __launch_bounds__(256) void prep_weights(
    const float* __restrict__ Wl0, const float* __restrict__ bl0, const float* __restrict__ Wr0,
    const float* __restrict__ Wl1, const float* __restrict__ bl1, const float* __restrict__ Wr1,
    const float* __restrict__ Wl2, const float* __restrict__ bl2, const float* __restrict__ Wr2,
    const float* __restrict__ Wla, const float* __restrict__ bla, const float* __restrict__ Wra,
    const float* __restrict__ Wf,  const float* __restrict__ bfv, const float* __restrict__ Wrf,
    const float* __restrict__ wt,
    unsigned short* __restrict__ WcatB, float* __restrict__ bias1,
    unsigned short* __restrict__ W2catB, float* __restrict__ bias2) {
    int idx = blockIdx.x * 256 + threadIdx.x;
    float w0 = wt[0], w1 = wt[1], w2 = wt[2];
    if (idx < 81920) {
        int f = idx / 640, k = idx % 640;   // [f][kcat]
        float v;
        if (k < 128)      v = w0 * Wl0[f * 128 + k];
        else if (k < 256) v = w1 * Wl1[f * 128 + (k - 128)];
        else if (k < 384) v = w2 * Wl2[f * 128 + (k - 256)];
        else if (k < 512) v = Wla[f * 128 + (k - 384)];
        else {
            int kk = k - 512;
            v = w0 * Wr0[f * 128 + kk] + w1 * Wr1[f * 128 + kk] +
                w2 * Wr2[f * 128 + kk] + Wra[f * 128 + kk];
        }
        WcatB[idx] = f2b(v);
    } else if (idx < 81920 + 32768) {
        int j = idx - 81920;
        int f = j >> 8, k = j & 255;        // [f][k], K=256
        W2catB[j] = f2b((k < 128) ? Wf[f * 128 + k] : Wrf[f * 128 + (k - 128)]);
    } else if (idx < 81920 + 32768 + 128) {
        int f = idx - (81920 + 32768);
        bias1[f] = w0 * bl0[f] + w1 * bl1[f] + w2 * bl2[f] + bla[f];
        bias2[f] = bfv[f];
    }
}

// ---------- CSR build (unified: node n's edges contiguous, [e0|e1|e2] order) ----------
__global__ __launch_bounds__(256) void count_deg(
    const int* __restrict__ e0, const int* __restrict__ e1, const int* __restrict__ e2,
    int* __restrict__ deg) {
    int gid = blockIdx.x * 256 + threadIdx.x;
    if (gid >= 3 * NE) return;
    int t = (gid < NE) ? 0 : ((gid < 2 * NE) ? 1 : 2);
    int i = gid - t * NE;
    const int* ep = (t == 0) ? e0 : ((t == 1) ? e1 : e2);
    atomicAdd(&deg[t * NN + ep[NE + i]], 1);
}

__global__ __launch_bounds__(256) void scan_local(
    const int* __restrict__ deg, int* __restrict__ rsloc, int* __restrict__ bsum) {
    __shared__ int sc[256];
    int b = blockIdx.x, tid = threadIdx.x;
    int seg = b / NBLKSEG, blk = b % NBLKSEG;
    int g0 = seg * NN;
    int base = blk * 2048 + tid * 8;
    int vals[8]; int tsum = 0;
#pragma unroll
    for (int j = 0; j < 8; ++j) {
        int l = base + j;
        int d = (l < NN) ? deg[g0 + l] : 0;
        vals[j] = tsum; tsum += d;
    }
    sc[tid] = tsum;
    __syncthreads();
    for (int off = 1; off < 256; off <<= 1) {
        int v = (tid >= off) ? sc[tid - off] : 0;
        __syncthreads();
        sc[tid] += v;
        __syncthreads();
    }
    int excl = sc[tid] - tsum;
#pragma unroll
    for (int j = 0; j < 8; ++j) {
        int l = base + j;
        if (l < NN) rsloc[g0 + l] = excl + vals[j];
    }
    if (tid == 255) bsum[b] = sc[255];
}

__global__ void scan_bsum(int* __restrict__ bsum) {
    int tid = threadIdx.x;
    if (tid < 3) {
        int run = 0;
        for (int b = 0; b < NBLKSEG; ++b) {
            int idx = tid * NBLKSEG + b;
            int t = bsum[idx]; bsum[idx] = run; run += t;
        }
    }
}

// per node: unified rowstart rU = r0+r1+r2; fillpos per type = segment starts inside [rU, rU+dall)
__global__ __launch_bounds__(256) void scan_fix(
    const int* __restrict__ deg, const int* __restrict__ rsloc, const int* __restrict__ bsum,
    int* __restrict__ fillpos, int* __restrict__ rowstartU, int* __restrict__ degall) {
    int blk = blockIdx.x, tid = threadIdx.x;
    int base = blk * 2048 + tid * 8;
    int o0 = bsum[blk], o1 = bsum[NBLKSEG + blk], o2 = bsum[2 * NBLKSEG + blk];
#pragma unroll
    for (int j = 0; j < 8; ++j) {
        int l = base + j;
        if (l < NN) {
            int d0 = deg[l], d1 = deg[NN + l], d2 = deg[2 * NN + l];
            int rU = (rsloc[l] + o0) + (rsloc[NN + l] + o1) + (rsloc[2 * NN + l] + o2);
            fillpos[l] = rU;
            fillpos[NN + l] = rU + d0;
            fillpos[2 * NN + l] = rU + d0 + d1;
            rowstartU[l] = rU;
            degall[l] = d0 + d1 + d2;
        }
    }
}

__global__ __launch_bounds__(256) void fill_csr(
    const int* __restrict__ e0, const int* __restrict__ e1, const int* __restrict__ e2,
    int* __restrict__ fillpos, int* __restrict__ csrU) {
    int gid = blockIdx.x * 256 + threadIdx.x;
    if (gid >= 3 * NE) return;
    int t = (gid < NE) ? 0 : ((gid < 2 * NE) ? 1 : 2);
    int i = gid - t * NE;
    const int* ep = (t == 0) ? e0 : ((t == 1) ? e1 : e2);
    int src = ep[i], dst = ep[NE + i];
    int p = atomicAdd(&fillpos[t * NN + dst], 1);
    csrU[p] = src;
}

// ---------- gather1: wave per node, unified CSR, guarded depth-5 load pipeline ----------
__global__ __launch_bounds__(256) void gather1(
    const unsigned short* __restrict__ featB,
    const int* __restrict__ deg, const int* __restrict__ rowstartU,
    const int* __restrict__ degall, const int* __restrict__ csrU,
    unsigned short* __restrict__ meanB) {
    int n = __builtin_amdgcn_readfirstlane((int)((blockIdx.x * 256 + threadIdx.x) >> 6));
    if (n >= NN) return;
    int lane = threadIdx.x & 63;
    int d0 = deg[n], d1 = deg[NN + n];
    int dall = degall[n];
    int b1 = d0, b2 = d0 + d1;
    const int* cp = csrU + rowstartU[n];

    float p0 = 0.f, p1 = 0.f;                 // cumulative sums
    float sA0 = 0.f, sA1 = 0.f;               // cum at b1
    float sB0 = 0.f, sB1 = 0.f;               // cum at b2

    unsigned f0 = 0, f1 = 0, f2 = 0, f3 = 0, f4 = 0;
    int i5 = 0, i6 = 0;
    {
        int i0 = 0, i1 = 0, i2 = 0, i3 = 0, i4 = 0;
        if (dall > 0) i0 = cp[0];
        if (dall > 1) i1 = cp[1];
        if (dall > 2) i2 = cp[2];
        if (dall > 3) i3 = cp[3];
        if (dall > 4) i4 = cp[4];
        if (dall > 5) i5 = cp[5];
        if (dall > 6) i6 = cp[6];
        if (dall > 0) f0 = *((const unsigned*)(featB + (size_t)i0 * DD) + lane);
        if (dall > 1) f1 = *((const unsigned*)(featB + (size_t)i1 * DD) + lane);
        if (dall > 2) f2 = *((const unsigned*)(featB + (size_t)i2 * DD) + lane);
        if (dall > 3) f3 = *((const unsigned*)(featB + (size_t)i3 * DD) + lane);
        if (dall > 4) f4 = *((const unsigned*)(featB + (size_t)i4 * DD) + lane);
    }
    for (int j = 0; j <= dall; ++j) {
        if (j == b1)   { sA0 = p0; sA1 = p1; }
        if (j == b2)   { sB0 = p0; sB1 = p1; }
        if (j == dall) break;
        unsigned u = f0;
        f0 = f1; f1 = f2; f2 = f3; f3 = f4;
        if (j + 5 < dall) f4 = *((const unsigned*)(featB + (size_t)i5 * DD) + lane);
        i5 = i6;
        if (j + 7 < dall) i6 = cp[j + 7];
        p0 += b2lo(u); p1 += b2hi(u);
    }

    int d2 = dall - b2;
    float inv0 = 1.0f / fmaxf((float)d0, 1.0f);
    float inv1 = 1.0f / fmaxf((float)d1, 1.0f);
    float inv2 = 1.0f / fmaxf((float)d2, 1.0f);
    float inva = 1.0f / fmaxf((float)dall, 1.0f);
    float m10 = sB0 - sA0, m11 = sB1 - sA1;
    float m20 = p0 - sB0,  m21 = p1 - sB1;
    unsigned* outp = (unsigned*)(meanB + (size_t)n * 512) + lane;
    __builtin_nontemporal_store(pack2(sA0 * inv0, sA1 * inv0), outp);
    __builtin_nontemporal_store(pack2(m10 * inv1, m11 * inv1), outp + 64);
    __builtin_nontemporal_store(pack2(m20 * inv2, m21 * inv2), outp + 128);
    __builtin_nontemporal_store(pack2(p0 * inva,  p1 * inva),  outp + 192);
}

// ---------- gemm1_tile: [128 nodes x 640] @ [640 x 128] MFMA, bias+relu, BN partials ----------
__global__ __launch_bounds__(256) void gemm1_tile(
    const unsigned short* __restrict__ meanB, const unsigned short* __restrict__ featB,
    const unsigned short* __restrict__ WcatB, const float* __restrict__ bias1,
    unsigned short* __restrict__ comb, float* __restrict__ partials) {
    __shared__ unsigned short ABs[65536 / 2];
    unsigned short* As = ABs;
    unsigned short* Bs = ABs + 16384;
    int tid = threadIdx.x;
    int wid = tid >> 6, lane = tid & 63;
    int quad = lane >> 4, m16 = lane & 15;
    int nb = blockIdx.x * 128;
    int mb = (wid & 1) * 64, fb = (wid >> 1) * 64;
    f32x4 acc[4][4];
#pragma unroll
    for (int mi = 0; mi < 4; ++mi)
#pragma unroll
        for (int fi = 0; fi < 4; ++fi) acc[mi][fi] = (f32x4){0.f, 0.f, 0.f, 0.f};

    for (int kc = 0; kc < 5; ++kc) {
        __syncthreads();
#pragma unroll
        for (int it = 0; it < 8; ++it) {
            int idx = it * 256 + tid;
            int row = idx >> 4, chunk = idx & 15;
            int s = chunk >> 2, q = chunk & 3;
            int gr = min(nb + row, NN - 1);
            u32x4 v = (kc < 4)
                ? __builtin_nontemporal_load((const u32x4*)(meanB + (size_t)gr * 512 + kc * 128 + chunk * 8))
                : *(const u32x4*)(featB + (size_t)gr * DD + chunk * 8);
            *(u32x4*)&As[(((s * 128 + row) * 4) + q) * 8] = v;
        }
#pragma unroll
        for (int it = 0; it < 8; ++it) {
            int idx = it * 256 + tid;
            int f = idx >> 4, chunk = idx & 15;
            int s = chunk >> 2, q = chunk & 3;
            u32x4 v = *(const u32x4*)(WcatB + (size_t)f * 640 + kc * 128 + chunk * 8);
            *(u32x4*)&Bs[(((s * 128 + f) * 4) + q) * 8] = v;
        }
        __syncthreads();
#pragma unroll
        for (int s = 0; s < 4; ++s) {
            bf16x8 av[4], bv[4];
#pragma unroll
            for (int mi = 0; mi < 4; ++mi)
                av[mi] = *(const bf16x8*)&As[(((s * 128 + mb + mi * 16 + m16) * 4) + quad) * 8];
#pragma unroll
            for (int fi = 0; fi < 4; ++fi)
                bv[fi] = *(const bf16x8*)&Bs[(((s * 128 + fb + fi * 16 + m16) * 4) + quad) * 8];
#pragma unroll
            for (int mi = 0; mi < 4; ++mi)
#pragma unroll
                for (int fi = 0; fi < 4; ++fi)
                    acc[mi][fi] = __builtin_amdgcn_mfma_f32_16x16x32_bf16(av[mi], bv[fi], acc[mi][fi], 0, 0, 0);
        }
    }
    __syncthreads();    // all waves done reading LDS; reuse for BN partials
    float* bnS = (float*)ABs;
    float* bnQ = bnS + 128;
    if (tid < 128) { bnS[tid] = 0.f; bnQ[tid] = 0.f; }
    __syncthreads();
#pragma unroll
    for (int fi = 0; fi < 4; ++fi) {
        int f = fb + fi * 16 + m16;
        float bb = bias1[f];
        float s = 0.f, q = 0.f;
#pragma unroll
        for (int mi = 0; mi < 4; ++mi) {
#pragma unroll
            for (int r = 0; r < 4; ++r) {
                int row = nb + mb + mi * 16 + quad * 4 + r;
                float v = fmaxf(acc[mi][fi][r] + bb, 0.f);
                if (row < NN) {
                    s += v; q += v * v;
                    comb[(size_t)row * DD + f] = f2b(v);
                }
            }
        }
        atomicAdd(&bnS[f], s);
        atomicAdd(&bnQ[f], q);
    }
    __syncthreads();
    if (tid < 128) {
        partials[(size_t)tid * NBLKG + blockIdx.x] = bnS[tid];
        partials[(size_t)(128 + tid) * NBLKG + blockIdx.x] = bnQ[tid];
    }
}

// ---------- BN finalize ----------
__global__ __launch_bounds__(256) void bnfin(
    const float* __restrict__ partials,
    const float* __restrict__ gamma, const float* __restrict__ beta,
    float* __restrict__ bnA, float* __restrict__ bnB) {
    __shared__ float rs[256], rq[256];
    int f = blockIdx.x, tid = threadIdx.x;
    float s = 0.f, q = 0.f;
    for (int r = tid; r < NBLKG; r += 256) {
        s += partials[(size_t)f * NBLKG + r];
        q += partials[(size_t)(128 + f) * NBLKG + r];
    }
    rs[tid] = s; rq[tid] = q;
    __syncthreads();
    for (int off = 128; off > 0; off >>= 1) {
        if (tid < off) { rs[tid] += rs[tid + off]; rq[tid] += rq[tid + off]; }
        __syncthreads();
    }
    if (tid == 0) {
        float mu = rs[0] / (float)NN;
        float var = fmaxf(rq[0] / (float)NN - mu * mu, 0.f);
        float a = gamma[f] * rsqrtf(var + 1e-5f);
        bnA[f] = a;
        bnB[f] = beta[f] - mu * a;
    }
}

// ---------- gather2: wave per node, unified CSR, guarded depth-5 pipeline; BN epilogue ----------
__global__ __launch_bounds__(256) void gather2(
    const unsigned short* __restrict__ comb,
    const int* __restrict__ rowstartU, const int* __restrict__ degall,
    const int* __restrict__ csrU,
    const float* __restrict__ bnA, const float* __restrict__ bnB,
    unsigned short* __restrict__ meanC) {
    int n = __builtin_amdgcn_readfirstlane((int)((blockIdx.x * 256 + threadIdx.x) >> 6));
    if (n >= NN) return;
    int lane = threadIdx.x & 63;
    int dall = degall[n];
    const int* cp = csrU + rowstartU[n];

    float p0 = 0.f, p1 = 0.f;
    unsigned f0 = 0, f1 = 0, f2 = 0, f3 = 0, f4 = 0;
    int i5 = 0, i6 = 0;
    {
        int i0 = 0, i1 = 0, i2 = 0, i3 = 0, i4 = 0;
        if (dall > 0) i0 = cp[0];
        if (dall > 1) i1 = cp[1];
        if (dall > 2) i2 = cp[2];
        if (dall > 3) i3 = cp[3];
        if (dall > 4) i4 = cp[4];
        if (dall > 5) i5 = cp[5];
        if (dall > 6) i6 = cp[6];
        if (dall > 0) f0 = *((const unsigned*)(comb + (size_t)i0 * DD) + lane);
        if (dall > 1) f1 = *((const unsigned*)(comb + (size_t)i1 * DD) + lane);
        if (dall > 2) f2 = *((const unsigned*)(comb + (size_t)i2 * DD) + lane);
        if (dall > 3) f3 = *((const unsigned*)(comb + (size_t)i3 * DD) + lane);
        if (dall > 4) f4 = *((const unsigned*)(comb + (size_t)i4 * DD) + lane);
    }
    for (int j = 0; j < dall; ++j) {
        unsigned u = f0;
        f0 = f1; f1 = f2; f2 = f3; f3 = f4;
        if (j + 5 < dall) f4 = *((const unsigned*)(comb + (size_t)i5 * DD) + lane);
        i5 = i6;
        if (j + 7 < dall) i6 = cp[j + 7];
        p0 += b2lo(u); p1 += b2hi(u);
    }

    float v0 = 0.f, v1 = 0.f;
    if (dall > 0) {
        float inv = 1.0f / (float)dall;
        float2 a = *(const float2*)&bnA[lane * 2];
        float2 b = *(const float2*)&bnB[lane * 2];
        v0 = a.x * (p0 * inv) + b.x;
        v1 = a.y * (p1 * inv) + b.y;
    }
    __builtin_nontemporal_store(pack2(v0, v1),
                                (unsigned*)(meanC + (size_t)n * DD) + lane);
}

// ---------- gemm2_tile: [128 x 256] @ [256 x 128], fp32 out ----------
__global__ __launch_bounds__(256) void gemm2_tile(
    const unsigned short* __restrict__ meanC, const unsigned short* __restrict__ comb,
    const float* __restrict__ bnA, const float* __restrict__ bnB,
    const unsigned short* __restrict__ W2catB, const float* __restrict__ bias2,
    float* __restrict__ out) {
    __shared__ unsigned short ABs[65536 / 2];
    unsigned short* As = ABs;
    unsigned short* Bs = ABs + 16384;
    int tid = threadIdx.x;
    int wid = tid >> 6, lane = tid & 63;
    int quad = lane >> 4, m16 = lane & 15;
    int nb = blockIdx.x * 128;
    int mb = (wid & 1) * 64, fb = (wid >> 1) * 64;
    f32x4 acc[4][4];
#pragma unroll
    for (int mi = 0; mi < 4; ++mi)
#pragma unroll
        for (int fi = 0; fi < 4; ++fi) acc[mi][fi] = (f32x4){0.f, 0.f, 0.f, 0.f};

    for (int kc = 0; kc < 2; ++kc) {
        __syncthreads();
#pragma unroll
        for (int it = 0; it < 8; ++it) {
            int idx = it * 256 + tid;
            int row = idx >> 4, chunk = idx & 15;
            int s = chunk >> 2, q = chunk & 3;
            int gr = min(nb + row, NN - 1);
            u32x4 v;
            if (kc == 0) {
                v = __builtin_nontemporal_load((const u32x4*)(meanC + (size_t)gr * DD + chunk * 8));
            } else {
                u32x4 c4 = *(const u32x4*)(comb + (size_t)gr * DD + chunk * 8);
                int cb = chunk * 8;
                float4 a0 = *(const float4*)&bnA[cb], a1 = *(const float4*)&bnA[cb + 4];
                float4 b0 = *(const float4*)&bnB[cb], b1 = *(const float4*)&bnB[cb + 4];
                v.x = pack2(a0.x * b2lo(c4.x) + b0.x, a0.y * b2hi(c4.x) + b0.y);
                v.y = pack2(a0.z * b2lo(c4.y) + b0.z, a0.w * b2hi(c4.y) + b0.w);
                v.z = pack2(a1.x * b2lo(c4.z) + b1.x, a1.y * b2hi(c4.z) + b1.y);
                v.w = pack2(a1.z * b2lo(c4.w) + b1.z, a1.w * b2hi(c4.w) + b1.w);
            }
            *(u32x4*)&As[(((s * 128 + row) * 4) + q) * 8] = v;
        }
#pragma unroll
        for (int it = 0; it < 8; ++it) {
            int idx = it * 256 + tid;
            int f = idx >> 4, chunk = idx & 15;
            int s = chunk >> 2, q = chunk & 3;
            u32x4 v = *(const u32x4*)(W2catB + (size_t)f * 256 + kc * 128 + chunk * 8);
            *(u32x4*)&Bs[(((s * 128 + f) * 4) + q) * 8] = v;
        }
        __syncthreads();
#pragma unroll
        for (int s = 0; s < 4; ++s) {
            bf16x8 av[4], bv[4];
#pragma unroll
            for (int mi = 0; mi < 4; ++mi)
                av[mi] = *(const bf16x8*)&As[(((s * 128 + mb + mi * 16 + m16) * 4) + quad) * 8];
#pragma unroll
            for (int fi = 0; fi < 4; ++fi)
                bv[fi] = *(const bf16x8*)&Bs[(((s * 128 + fb + fi * 16 + m16) * 4) + quad) * 8];
#pragma unroll
            for (int mi = 0; mi < 4; ++mi)
#pragma unroll
                for (int fi = 0; fi < 4; ++fi)
                    acc[mi][fi] = __builtin_amdgcn_mfma_f32_16x16x32_bf16(av[mi], bv[fi], acc[mi][fi], 0, 0, 0);
        }
    }
#pragma unroll
    for (int fi = 0; fi < 4; ++fi) {
        int f = fb + fi * 16 + m16;
        float bb = bias2[f];
#pragma unroll
        for (int mi = 0; mi < 4; ++mi) {
#pragma unroll
            for (int r = 0; r < 4; ++r) {
                int row = nb + mb + mi * 16 + quad * 4 + r;
                if (row < NN)
                    __builtin_nontemporal_store(acc[mi][fi][r] + bb,
                                                &out[(size_t)row * DD + f]);
            }
        }
    }
}

extern "C" void kernel_launch(void* const* d_in, const int* in_sizes, int n_in,
                              void* d_out, int out_size, void* d_ws, size_t ws_size,
                              hipStream_t stream) {
    const float* feat = (const float*)d_in[0];
    const int* e0 = (const int*)d_in[1];
    const int* e1 = (const int*)d_in[2];
    const int* e2 = (const int*)d_in[3];
    const float* Wl0 = (const float*)d_in[4];
    const float* bl0 = (const float*)d_in[5];
    const float* Wr0 = (const float*)d_in[6];
    const float* Wl1 = (const float*)d_in[7];
    const float* bl1 = (const float*)d_in[8];
    const float* Wr1 = (const float*)d_in[9];
    const float* Wl2 = (const float*)d_in[10];
    const float* bl2 = (const float*)d_in[11];
    const float* Wr2 = (const float*)d_in[12];
    const float* Wla = (const float*)d_in[13];
    const float* bla = (const float*)d_in[14];
    const float* Wra = (const float*)d_in[15];
    const float* Wf  = (const float*)d_in[16];
    const float* bfv = (const float*)d_in[17];
    const float* Wrf = (const float*)d_in[18];
    const float* gamma = (const float*)d_in[19];
    const float* beta  = (const float*)d_in[20];
    const float* wt    = (const float*)d_in[21];

    int* deg      = (int*)d_ws;              // 3*NN
    int* rsloc    = deg + 3 * NN;            // 3*NN
    int* fillpos  = rsloc + 3 * NN;          // 3*NN
    int* csrU     = fillpos + 3 * NN;        // 3*NE
    int* bsum     = csrU + 3 * NE;           // 147 (pad 160)
    int* rowstartU = bsum + 160;             // NN
    int* degall    = rowstartU + NN;         // NN
    float* partials = (float*)(degall + NN); // 256*NBLKG
    float* bias1  = partials + 256 * NBLKG;  // 128
    float* bias2  = bias1 + 128;             // 128
    float* bnA    = bias2 + 128;             // 128
    float* bnB    = bnA + 128;               // 128
    unsigned short* WcatB  = (unsigned short*)(bnB + 128);   // 128*640
    unsigned short* W2catB = WcatB + 81920;                  // 128*256
    unsigned short* comb   = W2catB + 32768;                 // NN*128
    unsigned short* featB  = comb + (size_t)NN * DD;         // NN*128
    unsigned short* meanB  = featB + (size_t)NN * DD;        // NN*512
    unsigned short* meanC  = meanB + (size_t)NN * 512;       // NN*128

    hipMemsetAsync(deg, 0, (size_t)3 * NN * sizeof(int), stream);

    feat_to_bf16<<<6250, 256, 0, stream>>>(feat, featB);
    prep_weights<<<449, 256, 0, stream>>>(Wl0, bl0, Wr0, Wl1, bl1, Wr1, Wl2, bl2, Wr2,
                                          Wla, bla, Wra, Wf, bfv, Wrf, wt,
                                          WcatB, bias1, W2catB, bias2);
    count_deg<<<3516, 256, 0, stream>>>(e0, e1, e2, deg);
    scan_local<<<147, 256, 0, stream>>>(deg, rsloc, bsum);
    scan_bsum<<<1, 64, 0, stream>>>(bsum);
    scan_fix<<<NBLKSEG, 256, 0, stream>>>(deg, rsloc, bsum, fillpos, rowstartU, degall);
    fill_csr<<<3516, 256, 0, stream>>>(e0, e1, e2, fillpos, csrU);

    gather1<<<25000, 256, 0, stream>>>(featB, deg, rowstartU, degall, csrU, meanB);
    gemm1_tile<<<NBLKG, 256, 0, stream>>>(meanB, featB, WcatB, bias1, comb, partials);
    bnfin<<<128, 256, 0, stream>>>(partials, gamma, beta, bnA, bnB);
    gather2<<<25000, 256, 0, stream>>>(comb, rowstartU, degall, csrU, bnA, bnB, meanC);
    gemm2_tile<<<NBLKG, 256, 0, stream>>>(meanC, comb, bnA, bnB, W2catB, bias2,
                                          (float*)d_out);
}

// Round 14
// 462.901 us; speedup vs baseline: 1.0109x; 1.0109x over previous
//
#include <hip/hip_runtime.h>

#define NN 100000
#define NE 300000
#define DD 128
#define NBLKG 782            // ceil(NN/128) gemm blocks
#define NBLKSEG 49           // ceil(NN/2048) scan blocks per segment

typedef short bf16x8 __attribute__((ext_vector_type(8)));
typedef float f32x4 __attribute__((ext_vector_type(4)));
typedef unsigned u32x4 __attribute__((ext_vector_type(4)));

__device__ __forceinline__ unsigned short f2b(float f) {
    union { float f; unsigned u; } c; c.f = f;
    unsigned u = c.u;
    return (unsigned short)((u + 0x7fffu + ((u >> 16) & 1u)) >> 16);
}
__device__ __forceinline__ float b2lo(unsigned u) {
    union { float f; unsigned u; } c; c.u = u << 16; return c.f;
}
__device__ __forceinline__ float b2hi(unsigned u) {
    union { float f; unsigned u; } c; c.u = u & 0xffff0000u; return c.f;
}
__device__ __forceinline__ unsigned pack2(float lo, float hi) {
    return (unsigned)f2b(lo) | ((unsigned)f2b(hi) << 16);
}

// ---------- prep_all: feat->bf16 | weight prep | degree count (independent, merged) ----------
#define NB_FEAT 6250
#define NB_WT   449
#define NB_DEG  3516
__global__ __launch_bounds__(256) void prep_all(
    const float* __restrict__ feat, unsigned short* __restrict__ fb,
    const float* __restrict__ Wl0, const float* __restrict__ bl0, const float* __restrict__ Wr0,
    const float* __restrict__ Wl1, const float* __restrict__ bl1, const float* __restrict__ Wr1,
    const float* __restrict__ Wl2, const float* __restrict__ bl2, const float* __restrict__ Wr2,
    const float* __restrict__ Wla, const float* __restrict__ bla, const float* __restrict__ Wra,
    const float* __restrict__ Wf,  const float* __restrict__ bfv, const float* __restrict__ Wrf,
    const float* __restrict__ wt,
    unsigned short* __restrict__ WcatB, float* __restrict__ bias1,
    unsigned short* __restrict__ W2catB, float* __restrict__ bias2,
    const int* __restrict__ e0, const int* __restrict__ e1, const int* __restrict__ e2,
    int* __restrict__ deg) {
    int b = blockIdx.x, tid = threadIdx.x;
    if (b < NB_FEAT) {
        int gid = b * 256 + tid;
        if (gid >= NN * 16) return;
        const f32x4* f4 = (const f32x4*)feat;
        f32x4 a = __builtin_nontemporal_load(&f4[gid * 2]);
        f32x4 c = __builtin_nontemporal_load(&f4[gid * 2 + 1]);
        uint4 o;
        o.x = pack2(a.x, a.y); o.y = pack2(a.z, a.w);
        o.z = pack2(c.x, c.y); o.w = pack2(c.z, c.w);
        ((uint4*)fb)[gid] = o;
    } else if (b < NB_FEAT + NB_WT) {
        int idx = (b - NB_FEAT) * 256 + tid;
        float w0 = wt[0], w1 = wt[1], w2 = wt[2];
        if (idx < 81920) {
            int f = idx / 640, k = idx % 640;
            float v;
            if (k < 128)      v = w0 * Wl0[f * 128 + k];
            else if (k < 256) v = w1 * Wl1[f * 128 + (k - 128)];
            else if (k < 384) v = w2 * Wl2[f * 128 + (k - 256)];
            else if (k < 512) v = Wla[f * 128 + (k - 384)];
            else {
                int kk = k - 512;
                v = w0 * Wr0[f * 128 + kk] + w1 * Wr1[f * 128 + kk] +
                    w2 * Wr2[f * 128 + kk] + Wra[f * 128 + kk];
            }
            WcatB[idx] = f2b(v);
        } else if (idx < 81920 + 32768) {
            int j = idx - 81920;
            int f = j >> 8, k = j & 255;
            W2catB[j] = f2b((k < 128) ? Wf[f * 128 + k] : Wrf[f * 128 + (k - 128)]);
        } else if (idx < 81920 + 32768 + 128) {
            int f = idx - (81920 + 32768);
            bias1[f] = w0 * bl0[f] + w1 * bl1[f] + w2 * bl2[f] + bla[f];
            bias2[f] = bfv[f];
        }
    } else {
        int gid = (b - NB_FEAT - NB_WT) * 256 + tid;
        if (gid >= 3 * NE) return;
        int t = (gid < NE) ? 0 : ((gid < 2 * NE) ? 1 : 2);
        int i = gid - t * NE;
        const int* ep = (t == 0) ? e0 : ((t == 1) ? e1 : e2);
        atomicAdd(&deg[t * NN + ep[NE + i]], 1);
    }
}

// ---------- CSR build (unified: node n's edges contiguous, [e0|e1|e2] order) ----------
__global__ __launch_bounds__(256) void scan_local(
    const int* __restrict__ deg, int* __restrict__ rsloc, int* __restrict__ bsum) {
    __shared__ int sc[256];
    int b = blockIdx.x, tid = threadIdx.x;
    int seg = b / NBLKSEG, blk = b % NBLKSEG;
    int g0 = seg * NN;
    int base = blk * 2048 + tid * 8;
    int vals[8]; int tsum = 0;
#pragma unroll
    for (int j = 0; j < 8; ++j) {
        int l = base + j;
        int d = (l < NN) ? deg[g0 + l] : 0;
        vals[j] = tsum; tsum += d;
    }
    sc[tid] = tsum;
    __syncthreads();
    for (int off = 1; off < 256; off <<= 1) {
        int v = (tid >= off) ? sc[tid - off] : 0;
        __syncthreads();
        sc[tid] += v;
        __syncthreads();
    }
    int excl = sc[tid] - tsum;
#pragma unroll
    for (int j = 0; j < 8; ++j) {
        int l = base + j;
        if (l < NN) rsloc[g0 + l] = excl + vals[j];
    }
    if (tid == 255) bsum[b] = sc[255];
}

__global__ void scan_bsum(int* __restrict__ bsum) {
    int tid = threadIdx.x;
    if (tid < 3) {
        int run = 0;
        for (int b = 0; b < NBLKSEG; ++b) {
            int idx = tid * NBLKSEG + b;
            int t = bsum[idx]; bsum[idx] = run; run += t;
        }
    }
}

// per node: unified rowstart rU = r0+r1+r2; fillpos per type = segment starts inside [rU, rU+dall)
__global__ __launch_bounds__(256) void scan_fix(
    const int* __restrict__ deg, const int* __restrict__ rsloc, const int* __restrict__ bsum,
    int* __restrict__ fillpos, int* __restrict__ rowstartU, int* __restrict__ degall) {
    int blk = blockIdx.x, tid = threadIdx.x;
    int base = blk * 2048 + tid * 8;
    int o0 = bsum[blk], o1 = bsum[NBLKSEG + blk], o2 = bsum[2 * NBLKSEG + blk];
#pragma unroll
    for (int j = 0; j < 8; ++j) {
        int l = base + j;
        if (l < NN) {
            int d0 = deg[l], d1 = deg[NN + l], d2 = deg[2 * NN + l];
            int rU = (rsloc[l] + o0) + (rsloc[NN + l] + o1) + (rsloc[2 * NN + l] + o2);
            fillpos[l] = rU;
            fillpos[NN + l] = rU + d0;
            fillpos[2 * NN + l] = rU + d0 + d1;
            rowstartU[l] = rU;
            degall[l] = d0 + d1 + d2;
        }
    }
}

__global__ __launch_bounds__(256) void fill_csr(
    const int* __restrict__ e0, const int* __restrict__ e1, const int* __restrict__ e2,
    int* __restrict__ fillpos, int* __restrict__ csrU) {
    int gid = blockIdx.x * 256 + threadIdx.x;
    if (gid >= 3 * NE) return;
    int t = (gid < NE) ? 0 : ((gid < 2 * NE) ? 1 : 2);
    int i = gid - t * NE;
    const int* ep = (t == 0) ? e0 : ((t == 1) ? e1 : e2);
    int src = ep[i], dst = ep[NE + i];
    int p = atomicAdd(&fillpos[t * NN + dst], 1);
    csrU[p] = src;
}

// ---------- gather1: wave per node, unified CSR, guarded depth-5 load pipeline ----------
__global__ __launch_bounds__(256) void gather1(
    const unsigned short* __restrict__ featB,
    const int* __restrict__ deg, const int* __restrict__ rowstartU,
    const int* __restrict__ degall, const int* __restrict__ csrU,
    unsigned short* __restrict__ meanB) {
    int n = __builtin_amdgcn_readfirstlane((int)((blockIdx.x * 256 + threadIdx.x) >> 6));
    if (n >= NN) return;
    int lane = threadIdx.x & 63;
    int d0 = deg[n], d1 = deg[NN + n];
    int dall = degall[n];
    int b1 = d0, b2 = d0 + d1;
    const int* cp = csrU + rowstartU[n];

    float p0 = 0.f, p1 = 0.f;                 // cumulative sums
    float sA0 = 0.f, sA1 = 0.f;               // cum at b1
    float sB0 = 0.f, sB1 = 0.f;               // cum at b2

    unsigned f0 = 0, f1 = 0, f2 = 0, f3 = 0, f4 = 0;
    int i5 = 0, i6 = 0;
    {
        int i0 = 0, i1 = 0, i2 = 0, i3 = 0, i4 = 0;
        if (dall > 0) i0 = cp[0];
        if (dall > 1) i1 = cp[1];
        if (dall > 2) i2 = cp[2];
        if (dall > 3) i3 = cp[3];
        if (dall > 4) i4 = cp[4];
        if (dall > 5) i5 = cp[5];
        if (dall > 6) i6 = cp[6];
        if (dall > 0) f0 = *((const unsigned*)(featB + (size_t)i0 * DD) + lane);
        if (dall > 1) f1 = *((const unsigned*)(featB + (size_t)i1 * DD) + lane);
        if (dall > 2) f2 = *((const unsigned*)(featB + (size_t)i2 * DD) + lane);
        if (dall > 3) f3 = *((const unsigned*)(featB + (size_t)i3 * DD) + lane);
        if (dall > 4) f4 = *((const unsigned*)(featB + (size_t)i4 * DD) + lane);
    }
    for (int j = 0; j <= dall; ++j) {
        if (j == b1)   { sA0 = p0; sA1 = p1; }
        if (j == b2)   { sB0 = p0; sB1 = p1; }
        if (j == dall) break;
        unsigned u = f0;
        f0 = f1; f1 = f2; f2 = f3; f3 = f4;
        if (j + 5 < dall) f4 = *((const unsigned*)(featB + (size_t)i5 * DD) + lane);
        i5 = i6;
        if (j + 7 < dall) i6 = cp[j + 7];
        p0 += b2lo(u); p1 += b2hi(u);
    }

    int d2 = dall - b2;
    float inv0 = 1.0f / fmaxf((float)d0, 1.0f);
    float inv1 = 1.0f / fmaxf((float)d1, 1.0f);
    float inv2 = 1.0f / fmaxf((float)d2, 1.0f);
    float inva = 1.0f / fmaxf((float)dall, 1.0f);
    float m10 = sB0 - sA0, m11 = sB1 - sA1;
    float m20 = p0 - sB0,  m21 = p1 - sB1;
    unsigned* outp = (unsigned*)(meanB + (size_t)n * 512) + lane;
    __builtin_nontemporal_store(pack2(sA0 * inv0, sA1 * inv0), outp);
    __builtin_nontemporal_store(pack2(m10 * inv1, m11 * inv1), outp + 64);
    __builtin_nontemporal_store(pack2(m20 * inv2, m21 * inv2), outp + 128);
    __builtin_nontemporal_store(pack2(p0 * inva,  p1 * inva),  outp + 192);
}

// ---------- gemm1_tile: [128 x 640] @ [640 x 128] MFMA; As/Bs row-major + XOR swizzle ----------
// Row-major [128][128 shorts] tiles; granule chunk XOR'd with (row&7): staging writes and
// fragment reads both <=2-way bank aliasing (r9-verified pattern, now applied to B too).
__global__ __launch_bounds__(256) void gemm1_tile(
    const unsigned short* __restrict__ meanB, const unsigned short* __restrict__ featB,
    const unsigned short* __restrict__ WcatB, const float* __restrict__ bias1,
    unsigned short* __restrict__ comb, float* __restrict__ partials) {
    __shared__ unsigned short ABs[65536 / 2];
    unsigned short* As = ABs;              // [128][128] row-major, swizzled
    unsigned short* Bs = ABs + 16384;      // [128][128] row-major, swizzled
    int tid = threadIdx.x;
    int wid = tid >> 6, lane = tid & 63;
    int quad = lane >> 4, m16 = lane & 15;
    int nb = blockIdx.x * 128;
    int mb = (wid & 1) * 64, fb = (wid >> 1) * 64;
    f32x4 acc[4][4];
#pragma unroll
    for (int mi = 0; mi < 4; ++mi)
#pragma unroll
        for (int fi = 0; fi < 4; ++fi) acc[mi][fi] = (f32x4){0.f, 0.f, 0.f, 0.f};

    for (int kc = 0; kc < 5; ++kc) {
        __syncthreads();
#pragma unroll
        for (int it = 0; it < 8; ++it) {
            int idx = it * 256 + tid;
            int row = idx >> 4, chunk = idx & 15;
            int gr = min(nb + row, NN - 1);
            u32x4 v = (kc < 4)
                ? __builtin_nontemporal_load((const u32x4*)(meanB + (size_t)gr * 512 + kc * 128 + chunk * 8))
                : *(const u32x4*)(featB + (size_t)gr * DD + chunk * 8);
            *(u32x4*)&As[row * 128 + ((chunk ^ (row & 7)) * 8)] = v;
        }
#pragma unroll
        for (int it = 0; it < 8; ++it) {
            int idx = it * 256 + tid;
            int f = idx >> 4, chunk = idx & 15;
            u32x4 v = *(const u32x4*)(WcatB + (size_t)f * 640 + kc * 128 + chunk * 8);
            *(u32x4*)&Bs[f * 128 + ((chunk ^ (f & 7)) * 8)] = v;
        }
        __syncthreads();
#pragma unroll
        for (int s = 0; s < 4; ++s) {
            bf16x8 av[4], bv[4];
#pragma unroll
            for (int mi = 0; mi < 4; ++mi) {
                int row = mb + mi * 16 + m16;
                av[mi] = *(const bf16x8*)&As[row * 128 + (((s * 4 + quad) ^ (row & 7)) * 8)];
            }
#pragma unroll
            for (int fi = 0; fi < 4; ++fi) {
                int f = fb + fi * 16 + m16;
                bv[fi] = *(const bf16x8*)&Bs[f * 128 + (((s * 4 + quad) ^ (f & 7)) * 8)];
            }
#pragma unroll
            for (int mi = 0; mi < 4; ++mi)
#pragma unroll
                for (int fi = 0; fi < 4; ++fi)
                    acc[mi][fi] = __builtin_amdgcn_mfma_f32_16x16x32_bf16(av[mi], bv[fi], acc[mi][fi], 0, 0, 0);
        }
    }
    __syncthreads();    // all waves done reading LDS; reuse for BN partials
    float* bnS = (float*)ABs;
    float* bnQ = bnS + 128;
    if (tid < 128) { bnS[tid] = 0.f; bnQ[tid] = 0.f; }
    __syncthreads();
#pragma unroll
    for (int fi = 0; fi < 4; ++fi) {
        int f = fb + fi * 16 + m16;
        float bb = bias1[f];
        float s = 0.f, q = 0.f;
#pragma unroll
        for (int mi = 0; mi < 4; ++mi) {
#pragma unroll
            for (int r = 0; r < 4; ++r) {
                int row = nb + mb + mi * 16 + quad * 4 + r;
                float v = fmaxf(acc[mi][fi][r] + bb, 0.f);
                if (row < NN) {
                    s += v; q += v * v;
                    comb[(size_t)row * DD + f] = f2b(v);
                }
            }
        }
        atomicAdd(&bnS[f], s);
        atomicAdd(&bnQ[f], q);
    }
    __syncthreads();
    if (tid < 128) {
        partials[(size_t)tid * NBLKG + blockIdx.x] = bnS[tid];
        partials[(size_t)(128 + tid) * NBLKG + blockIdx.x] = bnQ[tid];
    }
}

// ---------- BN finalize ----------
__global__ __launch_bounds__(256) void bnfin(
    const float* __restrict__ partials,
    const float* __restrict__ gamma, const float* __restrict__ beta,
    float* __restrict__ bnA, float* __restrict__ bnB) {
    __shared__ float rs[256], rq[256];
    int f = blockIdx.x, tid = threadIdx.x;
    float s = 0.f, q = 0.f;
    for (int r = tid; r < NBLKG; r += 256) {
        s += partials[(size_t)f * NBLKG + r];
        q += partials[(size_t)(128 + f) * NBLKG + r];
    }
    rs[tid] = s; rq[tid] = q;
    __syncthreads();
    for (int off = 128; off > 0; off >>= 1) {
        if (tid < off) { rs[tid] += rs[tid + off]; rq[tid] += rq[tid + off]; }
        __syncthreads();
    }
    if (tid == 0) {
        float mu = rs[0] / (float)NN;
        float var = fmaxf(rq[0] / (float)NN - mu * mu, 0.f);
        float a = gamma[f] * rsqrtf(var + 1e-5f);
        bnA[f] = a;
        bnB[f] = beta[f] - mu * a;
    }
}

// ---------- gather2: wave per node, unified CSR, guarded depth-5 pipeline; BN epilogue ----------
__global__ __launch_bounds__(256) void gather2(
    const unsigned short* __restrict__ comb,
    const int* __restrict__ rowstartU, const int* __restrict__ degall,
    const int* __restrict__ csrU,
    const float* __restrict__ bnA, const float* __restrict__ bnB,
    unsigned short* __restrict__ meanC) {
    int n = __builtin_amdgcn_readfirstlane((int)((blockIdx.x * 256 + threadIdx.x) >> 6));
    if (n >= NN) return;
    int lane = threadIdx.x & 63;
    int dall = degall[n];
    const int* cp = csrU + rowstartU[n];

    float p0 = 0.f, p1 = 0.f;
    unsigned f0 = 0, f1 = 0, f2 = 0, f3 = 0, f4 = 0;
    int i5 = 0, i6 = 0;
    {
        int i0 = 0, i1 = 0, i2 = 0, i3 = 0, i4 = 0;
        if (dall > 0) i0 = cp[0];
        if (dall > 1) i1 = cp[1];
        if (dall > 2) i2 = cp[2];
        if (dall > 3) i3 = cp[3];
        if (dall > 4) i4 = cp[4];
        if (dall > 5) i5 = cp[5];
        if (dall > 6) i6 = cp[6];
        if (dall > 0) f0 = *((const unsigned*)(comb + (size_t)i0 * DD) + lane);
        if (dall > 1) f1 = *((const unsigned*)(comb + (size_t)i1 * DD) + lane);
        if (dall > 2) f2 = *((const unsigned*)(comb + (size_t)i2 * DD) + lane);
        if (dall > 3) f3 = *((const unsigned*)(comb + (size_t)i3 * DD) + lane);
        if (dall > 4) f4 = *((const unsigned*)(comb + (size_t)i4 * DD) + lane);
    }
    for (int j = 0; j < dall; ++j) {
        unsigned u = f0;
        f0 = f1; f1 = f2; f2 = f3; f3 = f4;
        if (j + 5 < dall) f4 = *((const unsigned*)(comb + (size_t)i5 * DD) + lane);
        i5 = i6;
        if (j + 7 < dall) i6 = cp[j + 7];
        p0 += b2lo(u); p1 += b2hi(u);
    }

    float v0 = 0.f, v1 = 0.f;
    if (dall > 0) {
        float inv = 1.0f / (float)dall;
        float2 a = *(const float2*)&bnA[lane * 2];
        float2 b = *(const float2*)&bnB[lane * 2];
        v0 = a.x * (p0 * inv) + b.x;
        v1 = a.y * (p1 * inv) + b.y;
    }
    __builtin_nontemporal_store(pack2(v0, v1),
                                (unsigned*)(meanC + (size_t)n * DD) + lane);
}

// ---------- gemm2_tile: [128 x 256] @ [256 x 128]; As/Bs row-major + XOR swizzle ----------
__global__ __launch_bounds__(256) void gemm2_tile(
    const unsigned short* __restrict__ meanC, const unsigned short* __restrict__ comb,
    const float* __restrict__ bnA, const float* __restrict__ bnB,
    const unsigned short* __restrict__ W2catB, const float* __restrict__ bias2,
    float* __restrict__ out) {
    __shared__ unsigned short ABs[65536 / 2];
    unsigned short* As = ABs;
    unsigned short* Bs = ABs + 16384;
    int tid = threadIdx.x;
    int wid = tid >> 6, lane = tid & 63;
    int quad = lane >> 4, m16 = lane & 15;
    int nb = blockIdx.x * 128;
    int mb = (wid & 1) * 64, fb = (wid >> 1) * 64;
    f32x4 acc[4][4];
#pragma unroll
    for (int mi = 0; mi < 4; ++mi)
#pragma unroll
        for (int fi = 0; fi < 4; ++fi) acc[mi][fi] = (f32x4){0.f, 0.f, 0.f, 0.f};

    for (int kc = 0; kc < 2; ++kc) {
        __syncthreads();
#pragma unroll
        for (int it = 0; it < 8; ++it) {
            int idx = it * 256 + tid;
            int row = idx >> 4, chunk = idx & 15;
            int gr = min(nb + row, NN - 1);
            u32x4 v;
            if (kc == 0) {
                v = __builtin_nontemporal_load((const u32x4*)(meanC + (size_t)gr * DD + chunk * 8));
            } else {
                u32x4 c4 = *(const u32x4*)(comb + (size_t)gr * DD + chunk * 8);
                int cb = chunk * 8;
                float4 a0 = *(const float4*)&bnA[cb], a1 = *(const float4*)&bnA[cb + 4];
                float4 b0 = *(const float4*)&bnB[cb], b1 = *(const float4*)&bnB[cb + 4];
                v.x = pack2(a0.x * b2lo(c4.x) + b0.x, a0.y * b2hi(c4.x) + b0.y);
                v.y = pack2(a0.z * b2lo(c4.y) + b0.z, a0.w * b2hi(c4.y) + b0.w);
                v.z = pack2(a1.x * b2lo(c4.z) + b1.x, a1.y * b2hi(c4.z) + b1.y);
                v.w = pack2(a1.z * b2lo(c4.w) + b1.z, a1.w * b2hi(c4.w) + b1.w);
            }
            *(u32x4*)&As[row * 128 + ((chunk ^ (row & 7)) * 8)] = v;
        }
#pragma unroll
        for (int it = 0; it < 8; ++it) {
            int idx = it * 256 + tid;
            int f = idx >> 4, chunk = idx & 15;
            u32x4 v = *(const u32x4*)(W2catB + (size_t)f * 256 + kc * 128 + chunk * 8);
            *(u32x4*)&Bs[f * 128 + ((chunk ^ (f & 7)) * 8)] = v;
        }
        __syncthreads();
#pragma unroll
        for (int s = 0; s < 4; ++s) {
            bf16x8 av[4], bv[4];
#pragma unroll
            for (int mi = 0; mi < 4; ++mi) {
                int row = mb + mi * 16 + m16;
                av[mi] = *(const bf16x8*)&As[row * 128 + (((s * 4 + quad) ^ (row & 7)) * 8)];
            }
#pragma unroll
            for (int fi = 0; fi < 4; ++fi) {
                int f = fb + fi * 16 + m16;
                bv[fi] = *(const bf16x8*)&Bs[f * 128 + (((s * 4 + quad) ^ (f & 7)) * 8)];
            }
#pragma unroll
            for (int mi = 0; mi < 4; ++mi)
#pragma unroll
                for (int fi = 0; fi < 4; ++fi)
                    acc[mi][fi] = __builtin_amdgcn_mfma_f32_16x16x32_bf16(av[mi], bv[fi], acc[mi][fi], 0, 0, 0);
        }
    }
#pragma unroll
    for (int fi = 0; fi < 4; ++fi) {
        int f = fb + fi * 16 + m16;
        float bb = bias2[f];
#pragma unroll
        for (int mi = 0; mi < 4; ++mi) {
#pragma unroll
            for (int r = 0; r < 4; ++r) {
                int row = nb + mb + mi * 16 + quad * 4 + r;
                if (row < NN)
                    __builtin_nontemporal_store(acc[mi][fi][r] + bb,
                                                &out[(size_t)row * DD + f]);
            }
        }
    }
}

extern "C" void kernel_launch(void* const* d_in, const int* in_sizes, int n_in,
                              void* d_out, int out_size, void* d_ws, size_t ws_size,
                              hipStream_t stream) {
    const float* feat = (const float*)d_in[0];
    const int* e0 = (const int*)d_in[1];
    const int* e1 = (const int*)d_in[2];
    const int* e2 = (const int*)d_in[3];
    const float* Wl0 = (const float*)d_in[4];
    const float* bl0 = (const float*)d_in[5];
    const float* Wr0 = (const float*)d_in[6];
    const float* Wl1 = (const float*)d_in[7];
    const float* bl1 = (const float*)d_in[8];
    const float* Wr1 = (const float*)d_in[9];
    const float* Wl2 = (const float*)d_in[10];
    const float* bl2 = (const float*)d_in[11];
    const float* Wr2 = (const float*)d_in[12];
    const float* Wla = (const float*)d_in[13];
    const float* bla = (const float*)d_in[14];
    const float* Wra = (const float*)d_in[15];
    const float* Wf  = (const float*)d_in[16];
    const float* bfv = (const float*)d_in[17];
    const float* Wrf = (const float*)d_in[18];
    const float* gamma = (const float*)d_in[19];
    const float* beta  = (const float*)d_in[20];
    const float* wt    = (const float*)d_in[21];

    int* deg      = (int*)d_ws;              // 3*NN
    int* rsloc    = deg + 3 * NN;            // 3*NN
    int* fillpos  = rsloc + 3 * NN;          // 3*NN
    int* csrU     = fillpos + 3 * NN;        // 3*NE
    int* bsum     = csrU + 3 * NE;           // 147 (pad 160)
    int* rowstartU = bsum + 160;             // NN
    int* degall    = rowstartU + NN;         // NN
    float* partials = (float*)(degall + NN); // 256*NBLKG
    float* bias1  = partials + 256 * NBLKG;  // 128
    float* bias2  = bias1 + 128;             // 128
    float* bnA    = bias2 + 128;             // 128
    float* bnB    = bnA + 128;               // 128
    unsigned short* WcatB  = (unsigned short*)(bnB + 128);   // 128*640
    unsigned short* W2catB = WcatB + 81920;                  // 128*256
    unsigned short* comb   = W2catB + 32768;                 // NN*128
    unsigned short* featB  = comb + (size_t)NN * DD;         // NN*128
    unsigned short* meanB  = featB + (size_t)NN * DD;        // NN*512
    unsigned short* meanC  = meanB + (size_t)NN * 512;       // NN*128

    hipMemsetAsync(deg, 0, (size_t)3 * NN * sizeof(int), stream);

    prep_all<<<NB_FEAT + NB_WT + NB_DEG, 256, 0, stream>>>(
        feat, featB,
        Wl0, bl0, Wr0, Wl1, bl1, Wr1, Wl2, bl2, Wr2,
        Wla, bla, Wra, Wf, bfv, Wrf, wt,
        WcatB, bias1, W2catB, bias2,
        e0, e1, e2, deg);
    scan_local<<<147, 256, 0, stream>>>(deg, rsloc, bsum);
    scan_bsum<<<1, 64, 0, stream>>>(bsum);
    scan_fix<<<NBLKSEG, 256, 0, stream>>>(deg, rsloc, bsum, fillpos, rowstartU, degall);
    fill_csr<<<3516, 256, 0, stream>>>(e0, e1, e2, fillpos, csrU);

    gather1<<<25000, 256, 0, stream>>>(featB, deg, rowstartU, degall, csrU, meanB);
    gemm1_tile<<<NBLKG, 256, 0, stream>>>(meanB, featB, WcatB, bias1, comb, partials);
    bnfin<<<128, 256, 0, stream>>>(partials, gamma, beta, bnA, bnB);
    gather2<<<25000, 256, 0, stream>>>(comb, rowstartU, degall, csrU, bnA, bnB, meanC);
    gemm2_tile<<<NBLKG, 256, 0, stream>>>(meanC, comb, bnA, bnB, W2catB, bias2,
                                          (float*)d_out);
}

// Round 15
// 438.561 us; speedup vs baseline: 1.0670x; 1.0555x over previous
//
#include <hip/hip_runtime.h>

#define NN 100000
#define NE 300000
#define DD 128
#define NBLKG 782            // ceil(NN/128) gemm blocks
#define NBLKSEG 49           // ceil(NN/2048) scan blocks per segment
#define NPARTB 440           // fill_csr blocks per partition (8 partitions)

typedef short bf16x8 __attribute__((ext_vector_type(8)));
typedef float f32x4 __attribute__((ext_vector_type(4)));
typedef unsigned u32x4 __attribute__((ext_vector_type(4)));

__device__ __forceinline__ unsigned short f2b(float f) {
    union { float f; unsigned u; } c; c.f = f;
    unsigned u = c.u;
    return (unsigned short)((u + 0x7fffu + ((u >> 16) & 1u)) >> 16);
}
__device__ __forceinline__ float b2lo(unsigned u) {
    union { float f; unsigned u; } c; c.u = u << 16; return c.f;
}
__device__ __forceinline__ float b2hi(unsigned u) {
    union { float f; unsigned u; } c; c.u = u & 0xffff0000u; return c.f;
}
__device__ __forceinline__ unsigned pack2(float lo, float hi) {
    return (unsigned)f2b(lo) | ((unsigned)f2b(hi) << 16);
}

// ---------- prep_all: feat->bf16 | weight prep | degree count (independent, merged) ----------
#define NB_FEAT 6250
#define NB_WT   449
#define NB_DEG  3516
__global__ __launch_bounds__(256) void prep_all(
    const float* __restrict__ feat, unsigned short* __restrict__ fb,
    const float* __restrict__ Wl0, const float* __restrict__ bl0, const float* __restrict__ Wr0,
    const float* __restrict__ Wl1, const float* __restrict__ bl1, const float* __restrict__ Wr1,
    const float* __restrict__ Wl2, const float* __restrict__ bl2, const float* __restrict__ Wr2,
    const float* __restrict__ Wla, const float* __restrict__ bla, const float* __restrict__ Wra,
    const float* __restrict__ Wf,  const float* __restrict__ bfv, const float* __restrict__ Wrf,
    const float* __restrict__ wt,
    unsigned short* __restrict__ WcatB, float* __restrict__ bias1,
    unsigned short* __restrict__ W2catB, float* __restrict__ bias2,
    const int* __restrict__ e0, const int* __restrict__ e1, const int* __restrict__ e2,
    int* __restrict__ deg) {
    int b = blockIdx.x, tid = threadIdx.x;
    if (b < NB_FEAT) {
        int gid = b * 256 + tid;
        if (gid >= NN * 16) return;
        const f32x4* f4 = (const f32x4*)feat;
        f32x4 a = __builtin_nontemporal_load(&f4[gid * 2]);
        f32x4 c = __builtin_nontemporal_load(&f4[gid * 2 + 1]);
        uint4 o;
        o.x = pack2(a.x, a.y); o.y = pack2(a.z, a.w);
        o.z = pack2(c.x, c.y); o.w = pack2(c.z, c.w);
        ((uint4*)fb)[gid] = o;
    } else if (b < NB_FEAT + NB_WT) {
        int idx = (b - NB_FEAT) * 256 + tid;
        float w0 = wt[0], w1 = wt[1], w2 = wt[2];
        if (idx < 81920) {
            int f = idx / 640, k = idx % 640;
            float v;
            if (k < 128)      v = w0 * Wl0[f * 128 + k];
            else if (k < 256) v = w1 * Wl1[f * 128 + (k - 128)];
            else if (k < 384) v = w2 * Wl2[f * 128 + (k - 256)];
            else if (k < 512) v = Wla[f * 128 + (k - 384)];
            else {
                int kk = k - 512;
                v = w0 * Wr0[f * 128 + kk] + w1 * Wr1[f * 128 + kk] +
                    w2 * Wr2[f * 128 + kk] + Wra[f * 128 + kk];
            }
            WcatB[idx] = f2b(v);
        } else if (idx < 81920 + 32768) {
            int j = idx - 81920;
            int f = j >> 8, k = j & 255;
            W2catB[j] = f2b((k < 128) ? Wf[f * 128 + k] : Wrf[f * 128 + (k - 128)]);
        } else if (idx < 81920 + 32768 + 128) {
            int f = idx - (81920 + 32768);
            bias1[f] = w0 * bl0[f] + w1 * bl1[f] + w2 * bl2[f] + bla[f];
            bias2[f] = bfv[f];
        }
    } else {
        int gid = (b - NB_FEAT - NB_WT) * 256 + tid;
        if (gid >= 3 * NE) return;
        int t = (gid < NE) ? 0 : ((gid < 2 * NE) ? 1 : 2);
        int i = gid - t * NE;
        const int* ep = (t == 0) ? e0 : ((t == 1) ? e1 : e2);
        atomicAdd(&deg[t * NN + ep[NE + i]], 1);
    }
}

// ---------- CSR build (unified: node n's edges contiguous, [e0|e1|e2] order) ----------
__global__ __launch_bounds__(256) void scan_local(
    const int* __restrict__ deg, int* __restrict__ rsloc, int* __restrict__ bsum) {
    __shared__ int sc[256];
    int b = blockIdx.x, tid = threadIdx.x;
    int seg = b / NBLKSEG, blk = b % NBLKSEG;
    int g0 = seg * NN;
    int base = blk * 2048 + tid * 8;
    int vals[8]; int tsum = 0;
#pragma unroll
    for (int j = 0; j < 8; ++j) {
        int l = base + j;
        int d = (l < NN) ? deg[g0 + l] : 0;
        vals[j] = tsum; tsum += d;
    }
    sc[tid] = tsum;
    __syncthreads();
    for (int off = 1; off < 256; off <<= 1) {
        int v = (tid >= off) ? sc[tid - off] : 0;
        __syncthreads();
        sc[tid] += v;
        __syncthreads();
    }
    int excl = sc[tid] - tsum;
#pragma unroll
    for (int j = 0; j < 8; ++j) {
        int l = base + j;
        if (l < NN) rsloc[g0 + l] = excl + vals[j];
    }
    if (tid == 255) bsum[b] = sc[255];
}

__global__ void scan_bsum(int* __restrict__ bsum) {
    int tid = threadIdx.x;
    if (tid < 3) {
        int run = 0;
        for (int b = 0; b < NBLKSEG; ++b) {
            int idx = tid * NBLKSEG + b;
            int t = bsum[idx]; bsum[idx] = run; run += t;
        }
    }
}

// per node: unified rowstart rU = r0+r1+r2; fillpos per type = segment starts inside [rU, rU+dall)
__global__ __launch_bounds__(256) void scan_fix(
    const int* __restrict__ deg, const int* __restrict__ rsloc, const int* __restrict__ bsum,
    int* __restrict__ fillpos, int* __restrict__ rowstartU, int* __restrict__ degall) {
    int blk = blockIdx.x, tid = threadIdx.x;
    int base = blk * 2048 + tid * 8;
    int o0 = bsum[blk], o1 = bsum[NBLKSEG + blk], o2 = bsum[2 * NBLKSEG + blk];
#pragma unroll
    for (int j = 0; j < 8; ++j) {
        int l = base + j;
        if (l < NN) {
            int d0 = deg[l], d1 = deg[NN + l], d2 = deg[2 * NN + l];
            int rU = (rsloc[l] + o0) + (rsloc[NN + l] + o1) + (rsloc[2 * NN + l] + o2);
            fillpos[l] = rU;
            fillpos[NN + l] = rU + d0;
            fillpos[2 * NN + l] = rU + d0 + d1;
            rowstartU[l] = rU;
            degall[l] = d0 + d1 + d2;
        }
    }
}

// ---------- fill_csr: XCD-local scatter — partition p (blockIdx%8) owns dst in [p*12500,(p+1)*12500) ----------
// Each partition's fillpos slice (150KB) and csrU slice (~450KB) stay in ONE XCD's L2
// -> dirty lines coalesce, HBM writeback ~3.6MB instead of 900K x 64B amplification.
// Cost: 8x re-read of dst stream (28.8MB), served from per-XCD L2/L3.
__global__ __launch_bounds__(256) void fill_csr(
    const int* __restrict__ e0, const int* __restrict__ e1, const int* __restrict__ e2,
    int* __restrict__ fillpos, int* __restrict__ csrU) {
    int part = blockIdx.x & 7;
    int bseq = blockIdx.x >> 3;
    int tid = threadIdx.x;
    int lo = part * 12500, hi = lo + 12500;
    for (int base = bseq * 256; base < 3 * NE; base += NPARTB * 256) {
        int gid = base + tid;
        if (gid >= 3 * NE) continue;
        int t = (gid < NE) ? 0 : ((gid < 2 * NE) ? 1 : 2);
        int i = gid - t * NE;
        const int* ep = (t == 0) ? e0 : ((t == 1) ? e1 : e2);
        int dst = ep[NE + i];
        if (dst < lo || dst >= hi) continue;
        int src = ep[i];
        int p = atomicAdd(&fillpos[t * NN + dst], 1);
        csrU[p] = src;
    }
}

// ---------- gather1: wave per node, unified CSR, guarded depth-5 load pipeline ----------
__global__ __launch_bounds__(256) void gather1(
    const unsigned short* __restrict__ featB,
    const int* __restrict__ deg, const int* __restrict__ rowstartU,
    const int* __restrict__ degall, const int* __restrict__ csrU,
    unsigned short* __restrict__ meanB) {
    int n = __builtin_amdgcn_readfirstlane((int)((blockIdx.x * 256 + threadIdx.x) >> 6));
    if (n >= NN) return;
    int lane = threadIdx.x & 63;
    int d0 = deg[n], d1 = deg[NN + n];
    int dall = degall[n];
    int b1 = d0, b2 = d0 + d1;
    const int* cp = csrU + rowstartU[n];

    float p0 = 0.f, p1 = 0.f;                 // cumulative sums
    float sA0 = 0.f, sA1 = 0.f;               // cum at b1
    float sB0 = 0.f, sB1 = 0.f;               // cum at b2

    unsigned f0 = 0, f1 = 0, f2 = 0, f3 = 0, f4 = 0;
    int i5 = 0, i6 = 0;
    {
        int i0 = 0, i1 = 0, i2 = 0, i3 = 0, i4 = 0;
        if (dall > 0) i0 = cp[0];
        if (dall > 1) i1 = cp[1];
        if (dall > 2) i2 = cp[2];
        if (dall > 3) i3 = cp[3];
        if (dall > 4) i4 = cp[4];
        if (dall > 5) i5 = cp[5];
        if (dall > 6) i6 = cp[6];
        if (dall > 0) f0 = *((const unsigned*)(featB + (size_t)i0 * DD) + lane);
        if (dall > 1) f1 = *((const unsigned*)(featB + (size_t)i1 * DD) + lane);
        if (dall > 2) f2 = *((const unsigned*)(featB + (size_t)i2 * DD) + lane);
        if (dall > 3) f3 = *((const unsigned*)(featB + (size_t)i3 * DD) + lane);
        if (dall > 4) f4 = *((const unsigned*)(featB + (size_t)i4 * DD) + lane);
    }
    for (int j = 0; j <= dall; ++j) {
        if (j == b1)   { sA0 = p0; sA1 = p1; }
        if (j == b2)   { sB0 = p0; sB1 = p1; }
        if (j == dall) break;
        unsigned u = f0;
        f0 = f1; f1 = f2; f2 = f3; f3 = f4;
        if (j + 5 < dall) f4 = *((const unsigned*)(featB + (size_t)i5 * DD) + lane);
        i5 = i6;
        if (j + 7 < dall) i6 = cp[j + 7];
        p0 += b2lo(u); p1 += b2hi(u);
    }

    int d2 = dall - b2;
    float inv0 = 1.0f / fmaxf((float)d0, 1.0f);
    float inv1 = 1.0f / fmaxf((float)d1, 1.0f);
    float inv2 = 1.0f / fmaxf((float)d2, 1.0f);
    float inva = 1.0f / fmaxf((float)dall, 1.0f);
    float m10 = sB0 - sA0, m11 = sB1 - sA1;
    float m20 = p0 - sB0,  m21 = p1 - sB1;
    unsigned* outp = (unsigned*)(meanB + (size_t)n * 512) + lane;
    __builtin_nontemporal_store(pack2(sA0 * inv0, sA1 * inv0), outp);
    __builtin_nontemporal_store(pack2(m10 * inv1, m11 * inv1), outp + 64);
    __builtin_nontemporal_store(pack2(m20 * inv2, m21 * inv2), outp + 128);
    __builtin_nontemporal_store(pack2(p0 * inva,  p1 * inva),  outp + 192);
}

// ---------- gemm1_tile: [128 x 640] @ [640 x 128] MFMA; As/Bs row-major + XOR swizzle ----------
__global__ __launch_bounds__(256) void gemm1_tile(
    const unsigned short* __restrict__ meanB, const unsigned short* __restrict__ featB,
    const unsigned short* __restrict__ WcatB, const float* __restrict__ bias1,
    unsigned short* __restrict__ comb, float* __restrict__ partials) {
    __shared__ unsigned short ABs[65536 / 2];
    unsigned short* As = ABs;              // [128][128] row-major, swizzled
    unsigned short* Bs = ABs + 16384;      // [128][128] row-major, swizzled
    int tid = threadIdx.x;
    int wid = tid >> 6, lane = tid & 63;
    int quad = lane >> 4, m16 = lane & 15;
    int nb = blockIdx.x * 128;
    int mb = (wid & 1) * 64, fb = (wid >> 1) * 64;
    f32x4 acc[4][4];
#pragma unroll
    for (int mi = 0; mi < 4; ++mi)
#pragma unroll
        for (int fi = 0; fi < 4; ++fi) acc[mi][fi] = (f32x4){0.f, 0.f, 0.f, 0.f};

    for (int kc = 0; kc < 5; ++kc) {
        __syncthreads();
#pragma unroll
        for (int it = 0; it < 8; ++it) {
            int idx = it * 256 + tid;
            int row = idx >> 4, chunk = idx & 15;
            int gr = min(nb + row, NN - 1);
            u32x4 v = (kc < 4)
                ? __builtin_nontemporal_load((const u32x4*)(meanB + (size_t)gr * 512 + kc * 128 + chunk * 8))
                : *(const u32x4*)(featB + (size_t)gr * DD + chunk * 8);
            *(u32x4*)&As[row * 128 + ((chunk ^ (row & 7)) * 8)] = v;
        }
#pragma unroll
        for (int it = 0; it < 8; ++it) {
            int idx = it * 256 + tid;
            int f = idx >> 4, chunk = idx & 15;
            u32x4 v = *(const u32x4*)(WcatB + (size_t)f * 640 + kc * 128 + chunk * 8);
            *(u32x4*)&Bs[f * 128 + ((chunk ^ (f & 7)) * 8)] = v;
        }
        __syncthreads();
#pragma unroll
        for (int s = 0; s < 4; ++s) {
            bf16x8 av[4], bv[4];
#pragma unroll
            for (int mi = 0; mi < 4; ++mi) {
                int row = mb + mi * 16 + m16;
                av[mi] = *(const bf16x8*)&As[row * 128 + (((s * 4 + quad) ^ (row & 7)) * 8)];
            }
#pragma unroll
            for (int fi = 0; fi < 4; ++fi) {
                int f = fb + fi * 16 + m16;
                bv[fi] = *(const bf16x8*)&Bs[f * 128 + (((s * 4 + quad) ^ (f & 7)) * 8)];
            }
#pragma unroll
            for (int mi = 0; mi < 4; ++mi)
#pragma unroll
                for (int fi = 0; fi < 4; ++fi)
                    acc[mi][fi] = __builtin_amdgcn_mfma_f32_16x16x32_bf16(av[mi], bv[fi], acc[mi][fi], 0, 0, 0);
        }
    }
    __syncthreads();    // all waves done reading LDS; reuse for BN partials
    float* bnS = (float*)ABs;
    float* bnQ = bnS + 128;
    if (tid < 128) { bnS[tid] = 0.f; bnQ[tid] = 0.f; }
    __syncthreads();
#pragma unroll
    for (int fi = 0; fi < 4; ++fi) {
        int f = fb + fi * 16 + m16;
        float bb = bias1[f];
        float s = 0.f, q = 0.f;
#pragma unroll
        for (int mi = 0; mi < 4; ++mi) {
#pragma unroll
            for (int r = 0; r < 4; ++r) {
                int row = nb + mb + mi * 16 + quad * 4 + r;
                float v = fmaxf(acc[mi][fi][r] + bb, 0.f);
                if (row < NN) {
                    s += v; q += v * v;
                    comb[(size_t)row * DD + f] = f2b(v);
                }
            }
        }
        atomicAdd(&bnS[f], s);
        atomicAdd(&bnQ[f], q);
    }
    __syncthreads();
    if (tid < 128) {
        partials[(size_t)tid * NBLKG + blockIdx.x] = bnS[tid];
        partials[(size_t)(128 + tid) * NBLKG + blockIdx.x] = bnQ[tid];
    }
}

// ---------- BN finalize ----------
__global__ __launch_bounds__(256) void bnfin(
    const float* __restrict__ partials,
    const float* __restrict__ gamma, const float* __restrict__ beta,
    float* __restrict__ bnA, float* __restrict__ bnB) {
    __shared__ float rs[256], rq[256];
    int f = blockIdx.x, tid = threadIdx.x;
    float s = 0.f, q = 0.f;
    for (int r = tid; r < NBLKG; r += 256) {
        s += partials[(size_t)f * NBLKG + r];
        q += partials[(size_t)(128 + f) * NBLKG + r];
    }
    rs[tid] = s; rq[tid] = q;
    __syncthreads();
    for (int off = 128; off > 0; off >>= 1) {
        if (tid < off) { rs[tid] += rs[tid + off]; rq[tid] += rq[tid + off]; }
        __syncthreads();
    }
    if (tid == 0) {
        float mu = rs[0] / (float)NN;
        float var = fmaxf(rq[0] / (float)NN - mu * mu, 0.f);
        float a = gamma[f] * rsqrtf(var + 1e-5f);
        bnA[f] = a;
        bnB[f] = beta[f] - mu * a;
    }
}

// ---------- gather2: wave per node, unified CSR, guarded depth-5 pipeline; BN epilogue ----------
__global__ __launch_bounds__(256) void gather2(
    const unsigned short* __restrict__ comb,
    const int* __restrict__ rowstartU, const int* __restrict__ degall,
    const int* __restrict__ csrU,
    const float* __restrict__ bnA, const float* __restrict__ bnB,
    unsigned short* __restrict__ meanC) {
    int n = __builtin_amdgcn_readfirstlane((int)((blockIdx.x * 256 + threadIdx.x) >> 6));
    if (n >= NN) return;
    int lane = threadIdx.x & 63;
    int dall = degall[n];
    const int* cp = csrU + rowstartU[n];

    float p0 = 0.f, p1 = 0.f;
    unsigned f0 = 0, f1 = 0, f2 = 0, f3 = 0, f4 = 0;
    int i5 = 0, i6 = 0;
    {
        int i0 = 0, i1 = 0, i2 = 0, i3 = 0, i4 = 0;
        if (dall > 0) i0 = cp[0];
        if (dall > 1) i1 = cp[1];
        if (dall > 2) i2 = cp[2];
        if (dall > 3) i3 = cp[3];
        if (dall > 4) i4 = cp[4];
        if (dall > 5) i5 = cp[5];
        if (dall > 6) i6 = cp[6];
        if (dall > 0) f0 = *((const unsigned*)(comb + (size_t)i0 * DD) + lane);
        if (dall > 1) f1 = *((const unsigned*)(comb + (size_t)i1 * DD) + lane);
        if (dall > 2) f2 = *((const unsigned*)(comb + (size_t)i2 * DD) + lane);
        if (dall > 3) f3 = *((const unsigned*)(comb + (size_t)i3 * DD) + lane);
        if (dall > 4) f4 = *((const unsigned*)(comb + (size_t)i4 * DD) + lane);
    }
    for (int j = 0; j < dall; ++j) {
        unsigned u = f0;
        f0 = f1; f1 = f2; f2 = f3; f3 = f4;
        if (j + 5 < dall) f4 = *((const unsigned*)(comb + (size_t)i5 * DD) + lane);
        i5 = i6;
        if (j + 7 < dall) i6 = cp[j + 7];
        p0 += b2lo(u); p1 += b2hi(u);
    }

    float v0 = 0.f, v1 = 0.f;
    if (dall > 0) {
        float inv = 1.0f / (float)dall;
        float2 a = *(const float2*)&bnA[lane * 2];
        float2 b = *(const float2*)&bnB[lane * 2];
        v0 = a.x * (p0 * inv) + b.x;
        v1 = a.y * (p1 * inv) + b.y;
    }
    __builtin_nontemporal_store(pack2(v0, v1),
                                (unsigned*)(meanC + (size_t)n * DD) + lane);
}

// ---------- gemm2_tile: [128 x 256] @ [256 x 128]; As/Bs row-major + XOR swizzle ----------
__global__ __launch_bounds__(256) void gemm2_tile(
    const unsigned short* __restrict__ meanC, const unsigned short* __restrict__ comb,
    const float* __restrict__ bnA, const float* __restrict__ bnB,
    const unsigned short* __restrict__ W2catB, const float* __restrict__ bias2,
    float* __restrict__ out) {
    __shared__ unsigned short ABs[65536 / 2];
    unsigned short* As = ABs;
    unsigned short* Bs = ABs + 16384;
    int tid = threadIdx.x;
    int wid = tid >> 6, lane = tid & 63;
    int quad = lane >> 4, m16 = lane & 15;
    int nb = blockIdx.x * 128;
    int mb = (wid & 1) * 64, fb = (wid >> 1) * 64;
    f32x4 acc[4][4];
#pragma unroll
    for (int mi = 0; mi < 4; ++mi)
#pragma unroll
        for (int fi = 0; fi < 4; ++fi) acc[mi][fi] = (f32x4){0.f, 0.f, 0.f, 0.f};

    for (int kc = 0; kc < 2; ++kc) {
        __syncthreads();
#pragma unroll
        for (int it = 0; it < 8; ++it) {
            int idx = it * 256 + tid;
            int row = idx >> 4, chunk = idx & 15;
            int gr = min(nb + row, NN - 1);
            u32x4 v;
            if (kc == 0) {
                v = __builtin_nontemporal_load((const u32x4*)(meanC + (size_t)gr * DD + chunk * 8));
            } else {
                u32x4 c4 = *(const u32x4*)(comb + (size_t)gr * DD + chunk * 8);
                int cb = chunk * 8;
                float4 a0 = *(const float4*)&bnA[cb], a1 = *(const float4*)&bnA[cb + 4];
                float4 b0 = *(const float4*)&bnB[cb], b1 = *(const float4*)&bnB[cb + 4];
                v.x = pack2(a0.x * b2lo(c4.x) + b0.x, a0.y * b2hi(c4.x) + b0.y);
                v.y = pack2(a0.z * b2lo(c4.y) + b0.z, a0.w * b2hi(c4.y) + b0.w);
                v.z = pack2(a1.x * b2lo(c4.z) + b1.x, a1.y * b2hi(c4.z) + b1.y);
                v.w = pack2(a1.z * b2lo(c4.w) + b1.z, a1.w * b2hi(c4.w) + b1.w);
            }
            *(u32x4*)&As[row * 128 + ((chunk ^ (row & 7)) * 8)] = v;
        }
#pragma unroll
        for (int it = 0; it < 8; ++it) {
            int idx = it * 256 + tid;
            int f = idx >> 4, chunk = idx & 15;
            u32x4 v = *(const u32x4*)(W2catB + (size_t)f * 256 + kc * 128 + chunk * 8);
            *(u32x4*)&Bs[f * 128 + ((chunk ^ (f & 7)) * 8)] = v;
        }
        __syncthreads();
#pragma unroll
        for (int s = 0; s < 4; ++s) {
            bf16x8 av[4], bv[4];
#pragma unroll
            for (int mi = 0; mi < 4; ++mi) {
                int row = mb + mi * 16 + m16;
                av[mi] = *(const bf16x8*)&As[row * 128 + (((s * 4 + quad) ^ (row & 7)) * 8)];
            }
#pragma unroll
            for (int fi = 0; fi < 4; ++fi) {
                int f = fb + fi * 16 + m16;
                bv[fi] = *(const bf16x8*)&Bs[f * 128 + (((s * 4 + quad) ^ (f & 7)) * 8)];
            }
#pragma unroll
            for (int mi = 0; mi < 4; ++mi)
#pragma unroll
                for (int fi = 0; fi < 4; ++fi)
                    acc[mi][fi] = __builtin_amdgcn_mfma_f32_16x16x32_bf16(av[mi], bv[fi], acc[mi][fi], 0, 0, 0);
        }
    }
#pragma unroll
    for (int fi = 0; fi < 4; ++fi) {
        int f = fb + fi * 16 + m16;
        float bb = bias2[f];
#pragma unroll
        for (int mi = 0; mi < 4; ++mi) {
#pragma unroll
            for (int r = 0; r < 4; ++r) {
                int row = nb + mb + mi * 16 + quad * 4 + r;
                if (row < NN)
                    __builtin_nontemporal_store(acc[mi][fi][r] + bb,
                                                &out[(size_t)row * DD + f]);
            }
        }
    }
}

extern "C" void kernel_launch(void* const* d_in, const int* in_sizes, int n_in,
                              void* d_out, int out_size, void* d_ws, size_t ws_size,
                              hipStream_t stream) {
    const float* feat = (const float*)d_in[0];
    const int* e0 = (const int*)d_in[1];
    const int* e1 = (const int*)d_in[2];
    const int* e2 = (const int*)d_in[3];
    const float* Wl0 = (const float*)d_in[4];
    const float* bl0 = (const float*)d_in[5];
    const float* Wr0 = (const float*)d_in[6];
    const float* Wl1 = (const float*)d_in[7];
    const float* bl1 = (const float*)d_in[8];
    const float* Wr1 = (const float*)d_in[9];
    const float* Wl2 = (const float*)d_in[10];
    const float* bl2 = (const float*)d_in[11];
    const float* Wr2 = (const float*)d_in[12];
    const float* Wla = (const float*)d_in[13];
    const float* bla = (const float*)d_in[14];
    const float* Wra = (const float*)d_in[15];
    const float* Wf  = (const float*)d_in[16];
    const float* bfv = (const float*)d_in[17];
    const float* Wrf = (const float*)d_in[18];
    const float* gamma = (const float*)d_in[19];
    const float* beta  = (const float*)d_in[20];
    const float* wt    = (const float*)d_in[21];

    int* deg      = (int*)d_ws;              // 3*NN
    int* rsloc    = deg + 3 * NN;            // 3*NN
    int* fillpos  = rsloc + 3 * NN;          // 3*NN
    int* csrU     = fillpos + 3 * NN;        // 3*NE
    int* bsum     = csrU + 3 * NE;           // 147 (pad 160)
    int* rowstartU = bsum + 160;             // NN
    int* degall    = rowstartU + NN;         // NN
    float* partials = (float*)(degall + NN); // 256*NBLKG
    float* bias1  = partials + 256 * NBLKG;  // 128
    float* bias2  = bias1 + 128;             // 128
    float* bnA    = bias2 + 128;             // 128
    float* bnB    = bnA + 128;               // 128
    unsigned short* WcatB  = (unsigned short*)(bnB + 128);   // 128*640
    unsigned short* W2catB = WcatB + 81920;                  // 128*256
    unsigned short* comb   = W2catB + 32768;                 // NN*128
    unsigned short* featB  = comb + (size_t)NN * DD;         // NN*128
    unsigned short* meanB  = featB + (size_t)NN * DD;        // NN*512
    unsigned short* meanC  = meanB + (size_t)NN * 512;       // NN*128

    hipMemsetAsync(deg, 0, (size_t)3 * NN * sizeof(int), stream);

    prep_all<<<NB_FEAT + NB_WT + NB_DEG, 256, 0, stream>>>(
        feat, featB,
        Wl0, bl0, Wr0, Wl1, bl1, Wr1, Wl2, bl2, Wr2,
        Wla, bla, Wra, Wf, bfv, Wrf, wt,
        WcatB, bias1, W2catB, bias2,
        e0, e1, e2, deg);
    scan_local<<<147, 256, 0, stream>>>(deg, rsloc, bsum);
    scan_bsum<<<1, 64, 0, stream>>>(bsum);
    scan_fix<<<NBLKSEG, 256, 0, stream>>>(deg, rsloc, bsum, fillpos, rowstartU, degall);
    fill_csr<<<8 * NPARTB, 256, 0, stream>>>(e0, e1, e2, fillpos, csrU);

    gather1<<<25000, 256, 0, stream>>>(featB, deg, rowstartU, degall, csrU, meanB);
    gemm1_tile<<<NBLKG, 256, 0, stream>>>(meanB, featB, WcatB, bias1, comb, partials);
    bnfin<<<128, 256, 0, stream>>>(partials, gamma, beta, bnA, bnB);
    gather2<<<25000, 256, 0, stream>>>(comb, rowstartU, degall, csrU, bnA, bnB, meanC);
    gemm2_tile<<<NBLKG, 256, 0, stream>>>(meanC, comb, bnA, bnB, W2catB, bias2,
                                          (float*)d_out);
}

// Round 16
// 429.670 us; speedup vs baseline: 1.0891x; 1.0207x over previous
//
#include <hip/hip_runtime.h>

#define NN 100000
#define NE 300000
#define DD 128
#define NBLKG 782            // ceil(NN/128) gemm blocks
#define NBLKSEG 49           // ceil(NN/2048) scan blocks per segment
#define NPARTB 440           // fill_csr blocks per partition (8 partitions)

typedef short bf16x8 __attribute__((ext_vector_type(8)));
typedef float f32x4 __attribute__((ext_vector_type(4)));
typedef unsigned u32x4 __attribute__((ext_vector_type(4)));

__device__ __forceinline__ unsigned short f2b(float f) {
    union { float f; unsigned u; } c; c.f = f;
    unsigned u = c.u;
    return (unsigned short)((u + 0x7fffu + ((u >> 16) & 1u)) >> 16);
}
__device__ __forceinline__ float b2lo(unsigned u) {
    union { float f; unsigned u; } c; c.u = u << 16; return c.f;
}
__device__ __forceinline__ float b2hi(unsigned u) {
    union { float f; unsigned u; } c; c.u = u & 0xffff0000u; return c.f;
}
__device__ __forceinline__ unsigned pack2(float lo, float hi) {
    return (unsigned)f2b(lo) | ((unsigned)f2b(hi) << 16);
}

// ---------- prep_all: feat->bf16 | weight prep | degree count (independent, merged) ----------
#define NB_FEAT 6250
#define NB_WT   449
#define NB_DEG  3516
__global__ __launch_bounds__(256) void prep_all(
    const float* __restrict__ feat, unsigned short* __restrict__ fb,
    const float* __restrict__ Wl0, const float* __restrict__ bl0, const float* __restrict__ Wr0,
    const float* __restrict__ Wl1, const float* __restrict__ bl1, const float* __restrict__ Wr1,
    const float* __restrict__ Wl2, const float* __restrict__ bl2, const float* __restrict__ Wr2,
    const float* __restrict__ Wla, const float* __restrict__ bla, const float* __restrict__ Wra,
    const float* __restrict__ Wf,  const float* __restrict__ bfv, const float* __restrict__ Wrf,
    const float* __restrict__ wt,
    unsigned short* __restrict__ WcatB, float* __restrict__ bias1,
    unsigned short* __restrict__ W2catB, float* __restrict__ bias2,
    const int* __restrict__ e0, const int* __restrict__ e1, const int* __restrict__ e2,
    int* __restrict__ deg) {
    int b = blockIdx.x, tid = threadIdx.x;
    if (b < NB_FEAT) {
        int gid = b * 256 + tid;
        if (gid >= NN * 16) return;
        const f32x4* f4 = (const f32x4*)feat;
        f32x4 a = __builtin_nontemporal_load(&f4[gid * 2]);
        f32x4 c = __builtin_nontemporal_load(&f4[gid * 2 + 1]);
        uint4 o;
        o.x = pack2(a.x, a.y); o.y = pack2(a.z, a.w);
        o.z = pack2(c.x, c.y); o.w = pack2(c.z, c.w);
        ((uint4*)fb)[gid] = o;
    } else if (b < NB_FEAT + NB_WT) {
        int idx = (b - NB_FEAT) * 256 + tid;
        float w0 = wt[0], w1 = wt[1], w2 = wt[2];
        if (idx < 81920) {
            int f = idx / 640, k = idx % 640;
            float v;
            if (k < 128)      v = w0 * Wl0[f * 128 + k];
            else if (k < 256) v = w1 * Wl1[f * 128 + (k - 128)];
            else if (k < 384) v = w2 * Wl2[f * 128 + (k - 256)];
            else if (k < 512) v = Wla[f * 128 + (k - 384)];
            else {
                int kk = k - 512;
                v = w0 * Wr0[f * 128 + kk] + w1 * Wr1[f * 128 + kk] +
                    w2 * Wr2[f * 128 + kk] + Wra[f * 128 + kk];
            }
            WcatB[idx] = f2b(v);
        } else if (idx < 81920 + 32768) {
            int j = idx - 81920;
            int f = j >> 8, k = j & 255;
            W2catB[j] = f2b((k < 128) ? Wf[f * 128 + k] : Wrf[f * 128 + (k - 128)]);
        } else if (idx < 81920 + 32768 + 128) {
            int f = idx - (81920 + 32768);
            bias1[f] = w0 * bl0[f] + w1 * bl1[f] + w2 * bl2[f] + bla[f];
            bias2[f] = bfv[f];
        }
    } else {
        int gid = (b - NB_FEAT - NB_WT) * 256 + tid;
        if (gid >= 3 * NE) return;
        int t = (gid < NE) ? 0 : ((gid < 2 * NE) ? 1 : 2);
        int i = gid - t * NE;
        const int* ep = (t == 0) ? e0 : ((t == 1) ? e1 : e2);
        atomicAdd(&deg[t * NN + ep[NE + i]], 1);
    }
}

// ---------- CSR build (unified: node n's edges contiguous, [e0|e1|e2] order) ----------
__global__ __launch_bounds__(256) void scan_local(
    const int* __restrict__ deg, int* __restrict__ rsloc, int* __restrict__ bsum) {
    __shared__ int sc[256];
    int b = blockIdx.x, tid = threadIdx.x;
    int seg = b / NBLKSEG, blk = b % NBLKSEG;
    int g0 = seg * NN;
    int base = blk * 2048 + tid * 8;
    int vals[8]; int tsum = 0;
#pragma unroll
    for (int j = 0; j < 8; ++j) {
        int l = base + j;
        int d = (l < NN) ? deg[g0 + l] : 0;
        vals[j] = tsum; tsum += d;
    }
    sc[tid] = tsum;
    __syncthreads();
    for (int off = 1; off < 256; off <<= 1) {
        int v = (tid >= off) ? sc[tid - off] : 0;
        __syncthreads();
        sc[tid] += v;
        __syncthreads();
    }
    int excl = sc[tid] - tsum;
#pragma unroll
    for (int j = 0; j < 8; ++j) {
        int l = base + j;
        if (l < NN) rsloc[g0 + l] = excl + vals[j];
    }
    if (tid == 255) bsum[b] = sc[255];
}

__global__ void scan_bsum(int* __restrict__ bsum) {
    int tid = threadIdx.x;
    if (tid < 3) {
        int run = 0;
        for (int b = 0; b < NBLKSEG; ++b) {
            int idx = tid * NBLKSEG + b;
            int t = bsum[idx]; bsum[idx] = run; run += t;
        }
    }
}

// per node: unified rowstart rU = r0+r1+r2; fillpos per type = segment starts inside [rU, rU+dall)
__global__ __launch_bounds__(256) void scan_fix(
    const int* __restrict__ deg, const int* __restrict__ rsloc, const int* __restrict__ bsum,
    int* __restrict__ fillpos, int* __restrict__ rowstartU, int* __restrict__ degall) {
    int blk = blockIdx.x, tid = threadIdx.x;
    int base = blk * 2048 + tid * 8;
    int o0 = bsum[blk], o1 = bsum[NBLKSEG + blk], o2 = bsum[2 * NBLKSEG + blk];
#pragma unroll
    for (int j = 0; j < 8; ++j) {
        int l = base + j;
        if (l < NN) {
            int d0 = deg[l], d1 = deg[NN + l], d2 = deg[2 * NN + l];
            int rU = (rsloc[l] + o0) + (rsloc[NN + l] + o1) + (rsloc[2 * NN + l] + o2);
            fillpos[l] = rU;
            fillpos[NN + l] = rU + d0;
            fillpos[2 * NN + l] = rU + d0 + d1;
            rowstartU[l] = rU;
            degall[l] = d0 + d1 + d2;
        }
    }
}

// ---------- fill_csr: XCD-local scatter — partition p (blockIdx%8) owns dst in [p*12500,(p+1)*12500) ----------
__global__ __launch_bounds__(256) void fill_csr(
    const int* __restrict__ e0, const int* __restrict__ e1, const int* __restrict__ e2,
    int* __restrict__ fillpos, int* __restrict__ csrU) {
    int part = blockIdx.x & 7;
    int bseq = blockIdx.x >> 3;
    int tid = threadIdx.x;
    int lo = part * 12500, hi = lo + 12500;
    for (int base = bseq * 256; base < 3 * NE; base += NPARTB * 256) {
        int gid = base + tid;
        if (gid >= 3 * NE) continue;
        int t = (gid < NE) ? 0 : ((gid < 2 * NE) ? 1 : 2);
        int i = gid - t * NE;
        const int* ep = (t == 0) ? e0 : ((t == 1) ? e1 : e2);
        int dst = ep[NE + i];
        if (dst < lo || dst >= hi) continue;
        int src = ep[i];
        int p = atomicAdd(&fillpos[t * NN + dst], 1);
        csrU[p] = src;
    }
}

// ---------- gather1: wave per node, unified CSR, guarded depth-5 load pipeline ----------
__global__ __launch_bounds__(256) void gather1(
    const unsigned short* __restrict__ featB,
    const int* __restrict__ deg, const int* __restrict__ rowstartU,
    const int* __restrict__ degall, const int* __restrict__ csrU,
    unsigned short* __restrict__ meanB) {
    int n = __builtin_amdgcn_readfirstlane((int)((blockIdx.x * 256 + threadIdx.x) >> 6));
    if (n >= NN) return;
    int lane = threadIdx.x & 63;
    int d0 = deg[n], d1 = deg[NN + n];
    int dall = degall[n];
    int b1 = d0, b2 = d0 + d1;
    const int* cp = csrU + rowstartU[n];

    float p0 = 0.f, p1 = 0.f;                 // cumulative sums
    float sA0 = 0.f, sA1 = 0.f;               // cum at b1
    float sB0 = 0.f, sB1 = 0.f;               // cum at b2

    unsigned f0 = 0, f1 = 0, f2 = 0, f3 = 0, f4 = 0;
    int i5 = 0, i6 = 0;
    {
        int i0 = 0, i1 = 0, i2 = 0, i3 = 0, i4 = 0;
        if (dall > 0) i0 = cp[0];
        if (dall > 1) i1 = cp[1];
        if (dall > 2) i2 = cp[2];
        if (dall > 3) i3 = cp[3];
        if (dall > 4) i4 = cp[4];
        if (dall > 5) i5 = cp[5];
        if (dall > 6) i6 = cp[6];
        if (dall > 0) f0 = *((const unsigned*)(featB + (size_t)i0 * DD) + lane);
        if (dall > 1) f1 = *((const unsigned*)(featB + (size_t)i1 * DD) + lane);
        if (dall > 2) f2 = *((const unsigned*)(featB + (size_t)i2 * DD) + lane);
        if (dall > 3) f3 = *((const unsigned*)(featB + (size_t)i3 * DD) + lane);
        if (dall > 4) f4 = *((const unsigned*)(featB + (size_t)i4 * DD) + lane);
    }
    for (int j = 0; j <= dall; ++j) {
        if (j == b1)   { sA0 = p0; sA1 = p1; }
        if (j == b2)   { sB0 = p0; sB1 = p1; }
        if (j == dall) break;
        unsigned u = f0;
        f0 = f1; f1 = f2; f2 = f3; f3 = f4;
        if (j + 5 < dall) f4 = *((const unsigned*)(featB + (size_t)i5 * DD) + lane);
        i5 = i6;
        if (j + 7 < dall) i6 = cp[j + 7];
        p0 += b2lo(u); p1 += b2hi(u);
    }

    int d2 = dall - b2;
    float inv0 = 1.0f / fmaxf((float)d0, 1.0f);
    float inv1 = 1.0f / fmaxf((float)d1, 1.0f);
    float inv2 = 1.0f / fmaxf((float)d2, 1.0f);
    float inva = 1.0f / fmaxf((float)dall, 1.0f);
    float m10 = sB0 - sA0, m11 = sB1 - sA1;
    float m20 = p0 - sB0,  m21 = p1 - sB1;
    unsigned* outp = (unsigned*)(meanB + (size_t)n * 512) + lane;
    __builtin_nontemporal_store(pack2(sA0 * inv0, sA1 * inv0), outp);
    __builtin_nontemporal_store(pack2(m10 * inv1, m11 * inv1), outp + 64);
    __builtin_nontemporal_store(pack2(m20 * inv2, m21 * inv2), outp + 128);
    __builtin_nontemporal_store(pack2(p0 * inva,  p1 * inva),  outp + 192);
}

// ---------- gemm1_tile: [128 x 640] @ [640 x 128] MFMA; BK=64 -> 32KB LDS -> 4 blocks/CU ----------
// Same cooperative staging + XOR swizzle as the verified 64KB version, K chunked at 64
// (10 steps x 2 MFMA-K-slices). As/Bs = [128][64] shorts, chunk(0..7) ^ (row&7).
__global__ __launch_bounds__(256) void gemm1_tile(
    const unsigned short* __restrict__ meanB, const unsigned short* __restrict__ featB,
    const unsigned short* __restrict__ WcatB, const float* __restrict__ bias1,
    unsigned short* __restrict__ comb, float* __restrict__ partials) {
    __shared__ unsigned short ABs[32768 / 2];   // 32 KB
    unsigned short* As = ABs;              // [128][64] swizzled
    unsigned short* Bs = ABs + 8192;       // [128][64] swizzled
    int tid = threadIdx.x;
    int wid = tid >> 6, lane = tid & 63;
    int quad = lane >> 4, m16 = lane & 15;
    int nb = blockIdx.x * 128;
    int mb = (wid & 1) * 64, fb = (wid >> 1) * 64;
    f32x4 acc[4][4];
#pragma unroll
    for (int mi = 0; mi < 4; ++mi)
#pragma unroll
        for (int fi = 0; fi < 4; ++fi) acc[mi][fi] = (f32x4){0.f, 0.f, 0.f, 0.f};

    for (int kc = 0; kc < 10; ++kc) {
        __syncthreads();
#pragma unroll
        for (int it = 0; it < 4; ++it) {
            int idx = it * 256 + tid;
            int row = idx >> 3, chunk = idx & 7;
            int gr = min(nb + row, NN - 1);
            u32x4 v = (kc < 8)
                ? __builtin_nontemporal_load((const u32x4*)(meanB + (size_t)gr * 512 + kc * 64 + chunk * 8))
                : *(const u32x4*)(featB + (size_t)gr * DD + (kc - 8) * 64 + chunk * 8);
            *(u32x4*)&As[row * 64 + ((chunk ^ (row & 7)) * 8)] = v;
        }
#pragma unroll
        for (int it = 0; it < 4; ++it) {
            int idx = it * 256 + tid;
            int f = idx >> 3, chunk = idx & 7;
            u32x4 v = *(const u32x4*)(WcatB + (size_t)f * 640 + kc * 64 + chunk * 8);
            *(u32x4*)&Bs[f * 64 + ((chunk ^ (f & 7)) * 8)] = v;
        }
        __syncthreads();
#pragma unroll
        for (int s = 0; s < 2; ++s) {
            bf16x8 av[4], bv[4];
#pragma unroll
            for (int mi = 0; mi < 4; ++mi) {
                int row = mb + mi * 16 + m16;
                av[mi] = *(const bf16x8*)&As[row * 64 + (((s * 4 + quad) ^ (row & 7)) * 8)];
            }
#pragma unroll
            for (int fi = 0; fi < 4; ++fi) {
                int f = fb + fi * 16 + m16;
                bv[fi] = *(const bf16x8*)&Bs[f * 64 + (((s * 4 + quad) ^ (f & 7)) * 8)];
            }
#pragma unroll
            for (int mi = 0; mi < 4; ++mi)
#pragma unroll
                for (int fi = 0; fi < 4; ++fi)
                    acc[mi][fi] = __builtin_amdgcn_mfma_f32_16x16x32_bf16(av[mi], bv[fi], acc[mi][fi], 0, 0, 0);
        }
    }
    __syncthreads();    // all waves done reading LDS; reuse for BN partials
    float* bnS = (float*)ABs;
    float* bnQ = bnS + 128;
    if (tid < 128) { bnS[tid] = 0.f; bnQ[tid] = 0.f; }
    __syncthreads();
#pragma unroll
    for (int fi = 0; fi < 4; ++fi) {
        int f = fb + fi * 16 + m16;
        float bb = bias1[f];
        float s = 0.f, q = 0.f;
#pragma unroll
        for (int mi = 0; mi < 4; ++mi) {
#pragma unroll
            for (int r = 0; r < 4; ++r) {
                int row = nb + mb + mi * 16 + quad * 4 + r;
                float v = fmaxf(acc[mi][fi][r] + bb, 0.f);
                if (row < NN) {
                    s += v; q += v * v;
                    comb[(size_t)row * DD + f] = f2b(v);
                }
            }
        }
        atomicAdd(&bnS[f], s);
        atomicAdd(&bnQ[f], q);
    }
    __syncthreads();
    if (tid < 128) {
        partials[(size_t)tid * NBLKG + blockIdx.x] = bnS[tid];
        partials[(size_t)(128 + tid) * NBLKG + blockIdx.x] = bnQ[tid];
    }
}

// ---------- BN finalize ----------
__global__ __launch_bounds__(256) void bnfin(
    const float* __restrict__ partials,
    const float* __restrict__ gamma, const float* __restrict__ beta,
    float* __restrict__ bnA, float* __restrict__ bnB) {
    __shared__ float rs[256], rq[256];
    int f = blockIdx.x, tid = threadIdx.x;
    float s = 0.f, q = 0.f;
    for (int r = tid; r < NBLKG; r += 256) {
        s += partials[(size_t)f * NBLKG + r];
        q += partials[(size_t)(128 + f) * NBLKG + r];
    }
    rs[tid] = s; rq[tid] = q;
    __syncthreads();
    for (int off = 128; off > 0; off >>= 1) {
        if (tid < off) { rs[tid] += rs[tid + off]; rq[tid] += rq[tid + off]; }
        __syncthreads();
    }
    if (tid == 0) {
        float mu = rs[0] / (float)NN;
        float var = fmaxf(rq[0] / (float)NN - mu * mu, 0.f);
        float a = gamma[f] * rsqrtf(var + 1e-5f);
        bnA[f] = a;
        bnB[f] = beta[f] - mu * a;
    }
}

// ---------- gather2: wave per node, unified CSR, guarded depth-5 pipeline; BN epilogue ----------
__global__ __launch_bounds__(256) void gather2(
    const unsigned short* __restrict__ comb,
    const int* __restrict__ rowstartU, const int* __restrict__ degall,
    const int* __restrict__ csrU,
    const float* __restrict__ bnA, const float* __restrict__ bnB,
    unsigned short* __restrict__ meanC) {
    int n = __builtin_amdgcn_readfirstlane((int)((blockIdx.x * 256 + threadIdx.x) >> 6));
    if (n >= NN) return;
    int lane = threadIdx.x & 63;
    int dall = degall[n];
    const int* cp = csrU + rowstartU[n];

    float p0 = 0.f, p1 = 0.f;
    unsigned f0 = 0, f1 = 0, f2 = 0, f3 = 0, f4 = 0;
    int i5 = 0, i6 = 0;
    {
        int i0 = 0, i1 = 0, i2 = 0, i3 = 0, i4 = 0;
        if (dall > 0) i0 = cp[0];
        if (dall > 1) i1 = cp[1];
        if (dall > 2) i2 = cp[2];
        if (dall > 3) i3 = cp[3];
        if (dall > 4) i4 = cp[4];
        if (dall > 5) i5 = cp[5];
        if (dall > 6) i6 = cp[6];
        if (dall > 0) f0 = *((const unsigned*)(comb + (size_t)i0 * DD) + lane);
        if (dall > 1) f1 = *((const unsigned*)(comb + (size_t)i1 * DD) + lane);
        if (dall > 2) f2 = *((const unsigned*)(comb + (size_t)i2 * DD) + lane);
        if (dall > 3) f3 = *((const unsigned*)(comb + (size_t)i3 * DD) + lane);
        if (dall > 4) f4 = *((const unsigned*)(comb + (size_t)i4 * DD) + lane);
    }
    for (int j = 0; j < dall; ++j) {
        unsigned u = f0;
        f0 = f1; f1 = f2; f2 = f3; f3 = f4;
        if (j + 5 < dall) f4 = *((const unsigned*)(comb + (size_t)i5 * DD) + lane);
        i5 = i6;
        if (j + 7 < dall) i6 = cp[j + 7];
        p0 += b2lo(u); p1 += b2hi(u);
    }

    float v0 = 0.f, v1 = 0.f;
    if (dall > 0) {
        float inv = 1.0f / (float)dall;
        float2 a = *(const float2*)&bnA[lane * 2];
        float2 b = *(const float2*)&bnB[lane * 2];
        v0 = a.x * (p0 * inv) + b.x;
        v1 = a.y * (p1 * inv) + b.y;
    }
    __builtin_nontemporal_store(pack2(v0, v1),
                                (unsigned*)(meanC + (size_t)n * DD) + lane);
}

// ---------- gemm2_tile: [128 x 256] @ [256 x 128]; BK=64 -> 32KB LDS -> 4 blocks/CU ----------
__global__ __launch_bounds__(256) void gemm2_tile(
    const unsigned short* __restrict__ meanC, const unsigned short* __restrict__ comb,
    const float* __restrict__ bnA, const float* __restrict__ bnB,
    const unsigned short* __restrict__ W2catB, const float* __restrict__ bias2,
    float* __restrict__ out) {
    __shared__ unsigned short ABs[32768 / 2];
    unsigned short* As = ABs;
    unsigned short* Bs = ABs + 8192;
    int tid = threadIdx.x;
    int wid = tid >> 6, lane = tid & 63;
    int quad = lane >> 4, m16 = lane & 15;
    int nb = blockIdx.x * 128;
    int mb = (wid & 1) * 64, fb = (wid >> 1) * 64;
    f32x4 acc[4][4];
#pragma unroll
    for (int mi = 0; mi < 4; ++mi)
#pragma unroll
        for (int fi = 0; fi < 4; ++fi) acc[mi][fi] = (f32x4){0.f, 0.f, 0.f, 0.f};

    for (int kc = 0; kc < 4; ++kc) {
        __syncthreads();
#pragma unroll
        for (int it = 0; it < 4; ++it) {
            int idx = it * 256 + tid;
            int row = idx >> 3, chunk = idx & 7;
            int gr = min(nb + row, NN - 1);
            u32x4 v;
            if (kc < 2) {
                v = __builtin_nontemporal_load((const u32x4*)(meanC + (size_t)gr * DD + kc * 64 + chunk * 8));
            } else {
                int cb = (kc - 2) * 64 + chunk * 8;
                u32x4 c4 = *(const u32x4*)(comb + (size_t)gr * DD + cb);
                float4 a0 = *(const float4*)&bnA[cb], a1 = *(const float4*)&bnA[cb + 4];
                float4 b0 = *(const float4*)&bnB[cb], b1 = *(const float4*)&bnB[cb + 4];
                v.x = pack2(a0.x * b2lo(c4.x) + b0.x, a0.y * b2hi(c4.x) + b0.y);
                v.y = pack2(a0.z * b2lo(c4.y) + b0.z, a0.w * b2hi(c4.y) + b0.w);
                v.z = pack2(a1.x * b2lo(c4.z) + b1.x, a1.y * b2hi(c4.z) + b1.y);
                v.w = pack2(a1.z * b2lo(c4.w) + b1.z, a1.w * b2hi(c4.w) + b1.w);
            }
            *(u32x4*)&As[row * 64 + ((chunk ^ (row & 7)) * 8)] = v;
        }
#pragma unroll
        for (int it = 0; it < 4; ++it) {
            int idx = it * 256 + tid;
            int f = idx >> 3, chunk = idx & 7;
            u32x4 v = *(const u32x4*)(W2catB + (size_t)f * 256 + kc * 64 + chunk * 8);
            *(u32x4*)&Bs[f * 64 + ((chunk ^ (f & 7)) * 8)] = v;
        }
        __syncthreads();
#pragma unroll
        for (int s = 0; s < 2; ++s) {
            bf16x8 av[4], bv[4];
#pragma unroll
            for (int mi = 0; mi < 4; ++mi) {
                int row = mb + mi * 16 + m16;
                av[mi] = *(const bf16x8*)&As[row * 64 + (((s * 4 + quad) ^ (row & 7)) * 8)];
            }
#pragma unroll
            for (int fi = 0; fi < 4; ++fi) {
                int f = fb + fi * 16 + m16;
                bv[fi] = *(const bf16x8*)&Bs[f * 64 + (((s * 4 + quad) ^ (f & 7)) * 8)];
            }
#pragma unroll
            for (int mi = 0; mi < 4; ++mi)
#pragma unroll
                for (int fi = 0; fi < 4; ++fi)
                    acc[mi][fi] = __builtin_amdgcn_mfma_f32_16x16x32_bf16(av[mi], bv[fi], acc[mi][fi], 0, 0, 0);
        }
    }
#pragma unroll
    for (int fi = 0; fi < 4; ++fi) {
        int f = fb + fi * 16 + m16;
        float bb = bias2[f];
#pragma unroll
        for (int mi = 0; mi < 4; ++mi) {
#pragma unroll
            for (int r = 0; r < 4; ++r) {
                int row = nb + mb + mi * 16 + quad * 4 + r;
                if (row < NN)
                    __builtin_nontemporal_store(acc[mi][fi][r] + bb,
                                                &out[(size_t)row * DD + f]);
            }
        }
    }
}

extern "C" void kernel_launch(void* const* d_in, const int* in_sizes, int n_in,
                              void* d_out, int out_size, void* d_ws, size_t ws_size,
                              hipStream_t stream) {
    const float* feat = (const float*)d_in[0];
    const int* e0 = (const int*)d_in[1];
    const int* e1 = (const int*)d_in[2];
    const int* e2 = (const int*)d_in[3];
    const float* Wl0 = (const float*)d_in[4];
    const float* bl0 = (const float*)d_in[5];
    const float* Wr0 = (const float*)d_in[6];
    const float* Wl1 = (const float*)d_in[7];
    const float* bl1 = (const float*)d_in[8];
    const float* Wr1 = (const float*)d_in[9];
    const float* Wl2 = (const float*)d_in[10];
    const float* bl2 = (const float*)d_in[11];
    const float* Wr2 = (const float*)d_in[12];
    const float* Wla = (const float*)d_in[13];
    const float* bla = (const float*)d_in[14];
    const float* Wra = (const float*)d_in[15];
    const float* Wf  = (const float*)d_in[16];
    const float* bfv = (const float*)d_in[17];
    const float* Wrf = (const float*)d_in[18];
    const float* gamma = (const float*)d_in[19];
    const float* beta  = (const float*)d_in[20];
    const float* wt    = (const float*)d_in[21];

    int* deg      = (int*)d_ws;              // 3*NN
    int* rsloc    = deg + 3 * NN;            // 3*NN
    int* fillpos  = rsloc + 3 * NN;          // 3*NN
    int* csrU     = fillpos + 3 * NN;        // 3*NE
    int* bsum     = csrU + 3 * NE;           // 147 (pad 160)
    int* rowstartU = bsum + 160;             // NN
    int* degall    = rowstartU + NN;         // NN
    float* partials = (float*)(degall + NN); // 256*NBLKG
    float* bias1  = partials + 256 * NBLKG;  // 128
    float* bias2  = bias1 + 128;             // 128
    float* bnA    = bias2 + 128;             // 128
    float* bnB    = bnA + 128;               // 128
    unsigned short* WcatB  = (unsigned short*)(bnB + 128);   // 128*640
    unsigned short* W2catB = WcatB + 81920;                  // 128*256
    unsigned short* comb   = W2catB + 32768;                 // NN*128
    unsigned short* featB  = comb + (size_t)NN * DD;         // NN*128
    unsigned short* meanB  = featB + (size_t)NN * DD;        // NN*512
    unsigned short* meanC  = meanB + (size_t)NN * 512;       // NN*128

    hipMemsetAsync(deg, 0, (size_t)3 * NN * sizeof(int), stream);

    prep_all<<<NB_FEAT + NB_WT + NB_DEG, 256, 0, stream>>>(
        feat, featB,
        Wl0, bl0, Wr0, Wl1, bl1, Wr1, Wl2, bl2, Wr2,
        Wla, bla, Wra, Wf, bfv, Wrf, wt,
        WcatB, bias1, W2catB, bias2,
        e0, e1, e2, deg);
    scan_local<<<147, 256, 0, stream>>>(deg, rsloc, bsum);
    scan_bsum<<<1, 64, 0, stream>>>(bsum);
    scan_fix<<<NBLKSEG, 256, 0, stream>>>(deg, rsloc, bsum, fillpos, rowstartU, degall);
    fill_csr<<<8 * NPARTB, 256, 0, stream>>>(e0, e1, e2, fillpos, csrU);

    gather1<<<25000, 256, 0, stream>>>(featB, deg, rowstartU, degall, csrU, meanB);
    gemm1_tile<<<NBLKG, 256, 0, stream>>>(meanB, featB, WcatB, bias1, comb, partials);
    bnfin<<<128, 256, 0, stream>>>(partials, gamma, beta, bnA, bnB);
    gather2<<<25000, 256, 0, stream>>>(comb, rowstartU, degall, csrU, bnA, bnB, meanC);
    gemm2_tile<<<NBLKG, 256, 0, stream>>>(meanC, comb, bnA, bnB, W2catB, bias2,
                                          (float*)d_out);
}